// Round 2
// baseline (2181.910 us; speedup 1.0000x reference)
//
#include <hip/hip_runtime.h>

#define NN   4096
#define DM   256
#define NH   8
#define HDIM 32
#define NE   65536
#define ROWW 64   // u64 words per 4096-bit mask row

typedef unsigned short u16t;
typedef unsigned long long u64t;

// ---------------- mask build ----------------
__global__ __launch_bounds__(256) void edges_kernel(const int* __restrict__ ei, u64t* __restrict__ A){
  int e = blockIdx.x*256 + threadIdx.x;
  if (e < NE){
    int s = ei[e];
    int d = ei[NE + e];
    atomicOr(&A[(size_t)s*ROWW + (d>>6)], 1ull<<(d&63));
    atomicOr(&A[(size_t)d*ROWW + (s>>6)], 1ull<<(s&63));
  }
  if (e < NN){
    atomicOr(&A[(size_t)e*ROWW + (e>>6)], 1ull<<(e&63));
  }
}

// M[n] = OR_{k in row n of A} A[k]   (A symmetric incl self-loops => reach-2 mask)
__global__ __launch_bounds__(256) void reach2_kernel(const u64t* __restrict__ A, u64t* __restrict__ M){
  __shared__ u16t list[NN];
  __shared__ int  cnt;
  __shared__ u64t accs[256];
  const int tid = threadIdx.x;
  const int n   = blockIdx.x;
  const int t = tid & 63;   // word index
  const int g = tid >> 6;   // group 0..3
  if (tid==0) cnt=0;
  __syncthreads();
  if (tid < ROWW){
    u64t w = A[(size_t)n*ROWW + tid];
    int base = tid*64;
    while (w){
      int b = __builtin_ctzll(w);
      w &= w-1;
      int i = atomicAdd(&cnt,1);
      list[i] = (u16t)(base+b);
    }
  }
  __syncthreads();
  const int c = cnt;
  u64t acc = 0;
  for (int i=g; i<c; i+=4){
    acc |= A[(size_t)list[i]*ROWW + t];
  }
  accs[tid] = acc;
  __syncthreads();
  if (tid < ROWW){
    u64t a = accs[tid] | accs[64+tid] | accs[128+tid] | accs[192+tid];
    M[(size_t)n*ROWW + tid] = a;
  }
}

// ---------------- QKV projection ----------------
// X[4096,256] @ {Wq,Wk,Wv}[256,256] + bias.  Q scaled by 1/sqrt(32), fp32 [n][256].
// K,V stored fp32 head-major: [h][n][32].
__global__ __launch_bounds__(256) void qkv_kernel(const float* __restrict__ x,
    const float* __restrict__ Wq, const float* __restrict__ bq,
    const float* __restrict__ Wk, const float* __restrict__ bk,
    const float* __restrict__ Wv, const float* __restrict__ bv,
    float* __restrict__ Q, float* __restrict__ Kh, float* __restrict__ Vh)
{
  __shared__ __align__(16) float Xs[16*DM];
  const int j  = threadIdx.x;
  const int n0 = blockIdx.x*16;
  #pragma unroll
  for (int r=0;r<16;r++) Xs[r*DM+j] = x[(size_t)(n0+r)*DM + j];
  __syncthreads();
  float aq[16], ak[16], av[16];
  const float bqv=bq[j], bkv=bk[j], bvv=bv[j];
  #pragma unroll
  for (int r=0;r<16;r++){ aq[r]=bqv; ak[r]=bkv; av[r]=bvv; }
  for (int k=0;k<DM;k+=4){
    const float wq0=Wq[(k+0)*DM+j], wq1=Wq[(k+1)*DM+j], wq2=Wq[(k+2)*DM+j], wq3=Wq[(k+3)*DM+j];
    const float wk0=Wk[(k+0)*DM+j], wk1=Wk[(k+1)*DM+j], wk2=Wk[(k+2)*DM+j], wk3=Wk[(k+3)*DM+j];
    const float wv0=Wv[(k+0)*DM+j], wv1=Wv[(k+1)*DM+j], wv2=Wv[(k+2)*DM+j], wv3=Wv[(k+3)*DM+j];
    #pragma unroll
    for (int r=0;r<16;r++){
      float4 a = *(const float4*)&Xs[r*DM+k];
      aq[r] += a.x*wq0 + a.y*wq1 + a.z*wq2 + a.w*wq3;
      ak[r] += a.x*wk0 + a.y*wk1 + a.z*wk2 + a.w*wk3;
      av[r] += a.x*wv0 + a.y*wv1 + a.z*wv2 + a.w*wv3;
    }
  }
  const float qs = 0.17677669529663689f; // 1/sqrt(32)
  const int h = j>>5, d = j&31;
  #pragma unroll
  for (int r=0;r<16;r++){
    const int n = n0+r;
    Q[(size_t)n*DM + j] = aq[r]*qs;
    Kh[((size_t)h*NN + n)*HDIM + d] = ak[r];
    Vh[((size_t)h*NN + n)*HDIM + d] = av[r];
  }
}

// ---------------- sparse masked attention ----------------
// one block per query node n; loops over 8 heads; active-m list from mask bits.
__global__ __launch_bounds__(256) void attn_kernel(const u64t* __restrict__ M,
    const float* __restrict__ Q, const float* __restrict__ Kh, const float* __restrict__ Vh,
    float* __restrict__ att)
{
  __shared__ float qrow[DM];
  __shared__ u16t  list[NN];
  __shared__ float sc[NN];
  __shared__ float red[8];
  __shared__ float pv[256];
  __shared__ int   cnt;
  __shared__ float bc[2];
  const int tid = threadIdx.x;
  const int n   = blockIdx.x;
  if (tid==0) cnt=0;
  qrow[tid] = Q[(size_t)n*DM + tid];
  __syncthreads();
  if (tid < ROWW){
    u64t w = M[(size_t)n*ROWW + tid];
    int base = tid*64;
    while (w){
      int b = __builtin_ctzll(w);
      w &= w-1;
      int i = atomicAdd(&cnt,1);
      list[i] = (u16t)(base+b);
    }
  }
  __syncthreads();
  const int c = cnt;   // >=1 always (self-loop)
  for (int h=0; h<NH; h++){
    float qv[32];
    #pragma unroll
    for (int i=0;i<32;i++) qv[i] = qrow[h*32+i];
    const float* Kb = Kh + (size_t)h*NN*HDIM;
    for (int idx=tid; idx<c; idx+=256){
      const int m = list[idx];
      const float4* kp = (const float4*)(Kb + (size_t)m*HDIM);
      float acc = 0.f;
      #pragma unroll
      for (int q4=0;q4<8;q4++){
        float4 kv = kp[q4];
        acc += kv.x*qv[q4*4+0] + kv.y*qv[q4*4+1] + kv.z*qv[q4*4+2] + kv.w*qv[q4*4+3];
      }
      sc[idx] = acc;
    }
    __syncthreads();
    // row max
    float mx = -3e38f;
    for (int idx=tid; idx<c; idx+=256) mx = fmaxf(mx, sc[idx]);
    #pragma unroll
    for (int o=32;o>0;o>>=1) mx = fmaxf(mx, __shfl_down(mx,o));
    if ((tid&63)==0) red[tid>>6] = mx;
    __syncthreads();
    if (tid==0) bc[0] = fmaxf(fmaxf(red[0],red[1]), fmaxf(red[2],red[3]));
    __syncthreads();
    const float maxv = bc[0];
    // exp & sum
    float sm = 0.f;
    for (int idx=tid; idx<c; idx+=256){ float e=__expf(sc[idx]-maxv); sc[idx]=e; sm+=e; }
    #pragma unroll
    for (int o=32;o>0;o>>=1) sm += __shfl_down(sm,o);
    if ((tid&63)==0) red[tid>>6] = sm;
    __syncthreads();
    if (tid==0) bc[1] = red[0]+red[1]+red[2]+red[3];
    __syncthreads();
    const float inv = 1.f/bc[1];
    // P @ V
    const int d = tid&31, g = tid>>5;
    const float* Vb = Vh + (size_t)h*NN*HDIM;
    float acc = 0.f;
    for (int idx=g; idx<c; idx+=8){
      acc += sc[idx]*Vb[(size_t)list[idx]*HDIM + d];
    }
    pv[tid] = acc;
    __syncthreads();
    if (tid < 32){
      float a = 0.f;
      #pragma unroll
      for (int gg=0;gg<8;gg++) a += pv[gg*32+tid];
      att[(size_t)n*DM + h*32 + tid] = a*inv;
    }
    __syncthreads();
  }
}

// ---------------- output projection + residual + layernorm ----------------
__global__ __launch_bounds__(256) void outln_kernel(const float* __restrict__ att,
    const float* __restrict__ Wo, const float* __restrict__ bo,
    const float* __restrict__ x, const float* __restrict__ lnw, const float* __restrict__ lnb,
    float* __restrict__ out)
{
  __shared__ __align__(16) float As[16*DM];
  __shared__ float red[8];
  const int j  = threadIdx.x;
  const int n0 = blockIdx.x*16;
  #pragma unroll
  for (int r=0;r<16;r++) As[r*DM+j] = att[(size_t)(n0+r)*DM + j];
  __syncthreads();
  float acc[16];
  const float bov = bo[j];
  #pragma unroll
  for (int r=0;r<16;r++) acc[r]=bov;
  for (int k=0;k<DM;k+=4){
    const float w0=Wo[(k+0)*DM+j];
    const float w1=Wo[(k+1)*DM+j];
    const float w2=Wo[(k+2)*DM+j];
    const float w3=Wo[(k+3)*DM+j];
    #pragma unroll
    for (int r=0;r<16;r++){
      float4 a = *(const float4*)&As[r*DM+k];
      acc[r] += a.x*w0 + a.y*w1 + a.z*w2 + a.w*w3;
    }
  }
  const float lw=lnw[j], lb=lnb[j];
  #pragma unroll
  for (int r=0;r<16;r++) acc[r] += x[(size_t)(n0+r)*DM + j];  // residual
  for (int r=0;r<16;r++){
    const float v = acc[r];
    float s1=v, s2=v*v;
    #pragma unroll
    for (int o=32;o>0;o>>=1){ s1+=__shfl_down(s1,o); s2+=__shfl_down(s2,o); }
    if ((j&63)==0){ red[j>>6]=s1; red[4+(j>>6)]=s2; }
    __syncthreads();
    const float fs1 = red[0]+red[1]+red[2]+red[3];
    const float fs2 = red[4]+red[5]+red[6]+red[7];
    const float mu  = fs1*(1.0f/256.0f);
    const float var = fs2*(1.0f/256.0f) - mu*mu;
    const float ov  = (v-mu)*rsqrtf(var+1e-5f)*lw + lb;
    out[(size_t)(n0+r)*DM + j] = ov;
    __syncthreads();
  }
}

extern "C" void kernel_launch(void* const* d_in, const int* in_sizes, int n_in,
                              void* d_out, int out_size, void* d_ws, size_t ws_size,
                              hipStream_t stream) {
  const float* x   = (const float*)d_in[0];
  const int*   ei  = (const int*  )d_in[1];
  const float* Wq  = (const float*)d_in[2];
  const float* bq  = (const float*)d_in[3];
  const float* Wk  = (const float*)d_in[4];
  const float* bk  = (const float*)d_in[5];
  const float* Wv  = (const float*)d_in[6];
  const float* bv  = (const float*)d_in[7];
  const float* Wo  = (const float*)d_in[8];
  const float* bo  = (const float*)d_in[9];
  const float* lnw = (const float*)d_in[10];
  const float* lnb = (const float*)d_in[11];

  char* ws = (char*)d_ws;
  u64t*  A   = (u64t*)(ws);                      // 2 MiB adjacency bits
  u64t*  M   = (u64t*)(ws + (2u<<20));           // 2 MiB reach-2 bits
  float* Q   = (float*)(ws + (4u<<20));          // 4 MiB fp32 (pre-scaled)
  float* Kh  = (float*)(ws + (8u<<20));          // 4 MiB fp32 [h][n][32]
  float* Vh  = (float*)(ws + (12u<<20));         // 4 MiB fp32 [h][n][32]
  float* att = (float*)(ws + (16u<<20));         // 4 MiB fp32

  hipMemsetAsync(A, 0, (2u<<20), stream);
  edges_kernel<<<NE/256, 256, 0, stream>>>(ei, A);
  reach2_kernel<<<NN, 256, 0, stream>>>(A, M);
  qkv_kernel<<<NN/16, 256, 0, stream>>>(x, Wq,bq, Wk,bk, Wv,bv, Q, Kh, Vh);
  attn_kernel<<<NN, 256, 0, stream>>>(M, Q, Kh, Vh, att);
  outln_kernel<<<NN/16, 256, 0, stream>>>(att, Wo, bo, x, lnw, lnb, (float*)d_out);
}

// Round 3
// 301.131 us; speedup vs baseline: 7.2457x; 7.2457x over previous
//
#include <hip/hip_runtime.h>

#define NN   4096
#define DM   256
#define NH   8
#define HDIM 32
#define NE   65536
#define ROWW 64   // u64 words per 4096-bit mask row

typedef unsigned short u16t;
typedef unsigned int   u32t;
typedef unsigned long long u64t;
typedef __attribute__((ext_vector_type(8))) short bf16x8;
typedef __attribute__((ext_vector_type(4))) float f32x4;

__device__ __forceinline__ u16t f2bf(float f){
  u32t x; __builtin_memcpy(&x,&f,4);
  u32t r=(x+0x7fffu+((x>>16)&1u))>>16;
  return (u16t)r;
}

// async global->LDS, 16B per lane; lds dst is wave-uniform base (+lane*16 by HW)
__device__ __forceinline__ void gl2lds16(const void* g, void* l){
  auto gp = (const __attribute__((address_space(1))) u32t*)(unsigned long long)g;
  auto lp = (__attribute__((address_space(3))) u32t*)(u32t)(unsigned long long)l;
  __builtin_amdgcn_global_load_lds(gp, lp, 16, 0, 0);
}

// ---------------- mask build ----------------
__global__ __launch_bounds__(256) void edges_kernel(const int* __restrict__ ei, u64t* __restrict__ A){
  int e = blockIdx.x*256 + threadIdx.x;
  if (e < NE){
    int s = ei[e];
    int d = ei[NE + e];
    atomicOr(&A[(size_t)s*ROWW + (d>>6)], 1ull<<(d&63));
    atomicOr(&A[(size_t)d*ROWW + (s>>6)], 1ull<<(s&63));
  }
  if (e < NN){
    atomicOr(&A[(size_t)e*ROWW + (e>>6)], 1ull<<(e&63));
  }
}

__global__ __launch_bounds__(256) void reach2_kernel(const u64t* __restrict__ A, u64t* __restrict__ M){
  __shared__ u16t list[NN];
  __shared__ int  cnt;
  __shared__ u64t accs[256];
  const int tid = threadIdx.x;
  const int n   = blockIdx.x;
  const int t = tid & 63;
  const int g = tid >> 6;
  if (tid==0) cnt=0;
  __syncthreads();
  if (tid < ROWW){
    u64t w = A[(size_t)n*ROWW + tid];
    int base = tid*64;
    while (w){
      int b = __builtin_ctzll(w);
      w &= w-1;
      int i = atomicAdd(&cnt,1);
      list[i] = (u16t)(base+b);
    }
  }
  __syncthreads();
  const int c = cnt;
  u64t acc = 0;
  for (int i=g; i<c; i+=4){
    acc |= A[(size_t)list[i]*ROWW + t];
  }
  accs[tid] = acc;
  __syncthreads();
  if (tid < ROWW){
    u64t a = accs[tid] | accs[64+tid] | accs[128+tid] | accs[192+tid];
    M[(size_t)n*ROWW + tid] = a;
  }
}

// ---------------- QKV projection ----------------
// Q bf16 [h][n][32] pre-scaled by 1/sqrt(32); K bf16 [h][n][32]; V^T bf16 [h][32][n].
__global__ __launch_bounds__(256) void qkv_kernel(const float* __restrict__ x,
    const float* __restrict__ Wq, const float* __restrict__ bq,
    const float* __restrict__ Wk, const float* __restrict__ bk,
    const float* __restrict__ Wv, const float* __restrict__ bv,
    u16t* __restrict__ Qh, u16t* __restrict__ Kh, u16t* __restrict__ Vth)
{
  __shared__ __align__(16) float Xs[16*DM];
  const int j  = threadIdx.x;
  const int n0 = blockIdx.x*16;
  #pragma unroll
  for (int r=0;r<16;r++) Xs[r*DM+j] = x[(size_t)(n0+r)*DM + j];
  __syncthreads();
  float aq[16], ak[16], av[16];
  const float bqv=bq[j], bkv=bk[j], bvv=bv[j];
  #pragma unroll
  for (int r=0;r<16;r++){ aq[r]=bqv; ak[r]=bkv; av[r]=bvv; }
  for (int k=0;k<DM;k+=4){
    const float wq0=Wq[(k+0)*DM+j], wq1=Wq[(k+1)*DM+j], wq2=Wq[(k+2)*DM+j], wq3=Wq[(k+3)*DM+j];
    const float wk0=Wk[(k+0)*DM+j], wk1=Wk[(k+1)*DM+j], wk2=Wk[(k+2)*DM+j], wk3=Wk[(k+3)*DM+j];
    const float wv0=Wv[(k+0)*DM+j], wv1=Wv[(k+1)*DM+j], wv2=Wv[(k+2)*DM+j], wv3=Wv[(k+3)*DM+j];
    #pragma unroll
    for (int r=0;r<16;r++){
      float4 a = *(const float4*)&Xs[r*DM+k];
      aq[r] += a.x*wq0 + a.y*wq1 + a.z*wq2 + a.w*wq3;
      ak[r] += a.x*wk0 + a.y*wk1 + a.z*wk2 + a.w*wk3;
      av[r] += a.x*wv0 + a.y*wv1 + a.z*wv2 + a.w*wv3;
    }
  }
  const float qs = 0.17677669529663689f; // 1/sqrt(32)
  const int h = j>>5, d = j&31;
  #pragma unroll
  for (int r=0;r<16;r++){
    const int n = n0+r;
    Qh[((size_t)h*NN + n)*HDIM + d] = f2bf(aq[r]*qs);
    Kh[((size_t)h*NN + n)*HDIM + d] = f2bf(ak[r]);
    Vth[(size_t)h*HDIM*NN + (size_t)d*NN + n] = f2bf(av[r]);
  }
}

// ---------------- dense flash attention (MFMA) ----------------
// grid (64 q-tiles, 8 heads), 256 threads = 4 waves, wave owns 16 q-rows.
__global__ __launch_bounds__(256) void fattn_kernel(
    const u64t* __restrict__ M, const u16t* __restrict__ Qh,
    const u16t* __restrict__ Kh, const u16t* __restrict__ Vth,
    float* __restrict__ att)
{
  __shared__ __align__(16) u16t Ks[2][64*HDIM];   // K tile, swizzled chunks
  __shared__ __align__(16) u16t Vs[2][HDIM*64];   // V^T tile [d][key], swizzled
  __shared__ __align__(16) u64t Ms[2][64];        // mask word per q-row
  __shared__ __align__(16) u16t Ps[4][16*64];     // per-wave P (C->A layout hop), swizzled

  const int tid  = threadIdx.x;
  const int w    = tid >> 6;
  const int lane = tid & 63;
  const int l15  = lane & 15;
  const int quad = lane >> 4;
  const int h    = blockIdx.y;
  const int n0   = blockIdx.x * 64;

  const u16t* Kg = Kh  + (size_t)h*NN*HDIM;
  const u16t* Vg = Vth + (size_t)h*HDIM*NN;
  // staging inverse-swizzle offsets (phys chunk = tid -> logical global chunk)
  const int kr = tid>>2, kqp = tid&3;
  const int kgo = kr*HDIM + (kqp ^ ((kr>>1)&3))*8;   // + kt*2048
  const int vr = tid>>3, vqp = tid&7;
  const int vgo = vr*NN + (vqp ^ (vr&7))*8;          // + kt*64

  // Q A-fragment (rows w*16+l15, k-chunk quad*8..+7)
  bf16x8 qfrag;
  {
    const u16t* qp = Qh + ((size_t)h*NN + (n0 + w*16 + l15))*HDIM + quad*8;
    uint4 t = *(const uint4*)qp;
    __builtin_memcpy(&qfrag, &t, 16);
  }

  float mrow[4] = {-1e30f,-1e30f,-1e30f,-1e30f};
  float lrow[4] = {0.f,0.f,0.f,0.f};
  f32x4 Oacc[2] = {{0.f,0.f,0.f,0.f},{0.f,0.f,0.f,0.f}};
  const f32x4 zero = {0.f,0.f,0.f,0.f};

  // stage tile kt into buffer buf
  #define STAGE(kt, buf) do { \
    gl2lds16(Kg + (size_t)(kt)*2048 + kgo, &Ks[(buf)][w*512]); \
    gl2lds16(Vg + (size_t)(kt)*64 + vgo,  &Vs[(buf)][w*512]); \
    if (tid < 64) Ms[(buf)][tid] = M[(size_t)(n0+tid)*ROWW + (kt)]; \
  } while(0)

  STAGE(0, 0);
  const int kswz = (l15>>1)&3;
  const int pswz = l15&7;

  for (int kt=0; kt<64; ++kt){
    __syncthreads();                       // drains staging (vmcnt) + orders buffers
    if (kt < 63) STAGE(kt+1, (kt+1)&1);
    const int buf = kt&1;

    // S = Q K^T : 4 MFMAs (key groups of 16)
    f32x4 S[4];
    #pragma unroll
    for (int g=0; g<4; ++g){
      const u16t* kp = &Ks[buf][(g*16+l15)*HDIM + (quad ^ kswz)*8];
      uint4 t = *(const uint4*)kp;
      bf16x8 kb; __builtin_memcpy(&kb,&t,16);
      S[g] = __builtin_amdgcn_mfma_f32_16x16x32_bf16(qfrag, kb, zero, 0,0,0);
    }

    // mask (bit key of row word); masked -> -1e9 (junk flushed later by alpha=0)
    u64t mw[4];
    #pragma unroll
    for (int r=0;r<4;r++) mw[r] = Ms[buf][quad*4+r];
    #pragma unroll
    for (int g=0; g<4; ++g){
      const int key = g*16 + l15;
      #pragma unroll
      for (int r=0;r<4;r++){
        const bool on = (mw[r] >> key) & 1ull;
        S[g][r] = on ? S[g][r] : -1e9f;
      }
    }

    // online softmax per owned row (quad*4+r); reduce across the 16 lanes of the quad
    #pragma unroll
    for (int r=0;r<4;r++){
      float tmax = fmaxf(fmaxf(S[0][r],S[1][r]), fmaxf(S[2][r],S[3][r]));
      tmax = fmaxf(tmax, __shfl_xor(tmax,1));
      tmax = fmaxf(tmax, __shfl_xor(tmax,2));
      tmax = fmaxf(tmax, __shfl_xor(tmax,4));
      tmax = fmaxf(tmax, __shfl_xor(tmax,8));
      const float mn = fmaxf(mrow[r], tmax);
      const float a  = __expf(mrow[r]-mn);
      mrow[r]=mn;
      float ps=0.f;
      #pragma unroll
      for (int g=0;g<4;g++){ float p=__expf(S[g][r]-mn); S[g][r]=p; ps+=p; }
      ps += __shfl_xor(ps,1); ps += __shfl_xor(ps,2); ps += __shfl_xor(ps,4); ps += __shfl_xor(ps,8);
      lrow[r] = lrow[r]*a + ps;
      Oacc[0][r]*=a; Oacc[1][r]*=a;
    }

    // P: C-layout -> LDS (bf16, swizzled) -> A-layout
    #pragma unroll
    for (int g=0; g<4; ++g){
      const int ch = g*2 + (l15>>3);
      #pragma unroll
      for (int r=0;r<4;r++){
        const int pr = quad*4+r;
        Ps[w][pr*64 + (ch ^ (pr&7))*8 + (l15&7)] = f2bf(S[g][r]);
      }
    }

    // O += P V : 2 key-chunks x 2 d-halves
    #pragma unroll
    for (int kc=0; kc<2; ++kc){
      const u16t* pp = &Ps[w][l15*64 + ((kc*4+quad) ^ pswz)*8];
      uint4 ta = *(const uint4*)pp;
      bf16x8 pa; __builtin_memcpy(&pa,&ta,16);
      #pragma unroll
      for (int dh=0; dh<2; ++dh){
        const u16t* vp = &Vs[buf][(dh*16+l15)*64 + ((kc*4+quad) ^ pswz)*8];
        uint4 tb = *(const uint4*)vp;
        bf16x8 vb; __builtin_memcpy(&vb,&tb,16);
        Oacc[dh] = __builtin_amdgcn_mfma_f32_16x16x32_bf16(pa, vb, Oacc[dh], 0,0,0);
      }
    }
  }
  #undef STAGE

  // epilogue: O/l -> att fp32 [n][h*32+d]
  #pragma unroll
  for (int r=0;r<4;r++){
    const float inv = 1.f/lrow[r];
    const int n = n0 + w*16 + quad*4 + r;
    float* op = att + (size_t)n*DM + h*HDIM;
    op[l15]    = Oacc[0][r]*inv;
    op[16+l15] = Oacc[1][r]*inv;
  }
}

// ---------------- output projection + residual + layernorm ----------------
__global__ __launch_bounds__(256) void outln_kernel(const float* __restrict__ att,
    const float* __restrict__ Wo, const float* __restrict__ bo,
    const float* __restrict__ x, const float* __restrict__ lnw, const float* __restrict__ lnb,
    float* __restrict__ out)
{
  __shared__ __align__(16) float As[16*DM];
  __shared__ float red[8];
  const int j  = threadIdx.x;
  const int n0 = blockIdx.x*16;
  #pragma unroll
  for (int r=0;r<16;r++) As[r*DM+j] = att[(size_t)(n0+r)*DM + j];
  __syncthreads();
  float acc[16];
  const float bov = bo[j];
  #pragma unroll
  for (int r=0;r<16;r++) acc[r]=bov;
  for (int k=0;k<DM;k+=4){
    const float w0=Wo[(k+0)*DM+j];
    const float w1=Wo[(k+1)*DM+j];
    const float w2=Wo[(k+2)*DM+j];
    const float w3=Wo[(k+3)*DM+j];
    #pragma unroll
    for (int r=0;r<16;r++){
      float4 a = *(const float4*)&As[r*DM+k];
      acc[r] += a.x*w0 + a.y*w1 + a.z*w2 + a.w*w3;
    }
  }
  const float lw=lnw[j], lb=lnb[j];
  #pragma unroll
  for (int r=0;r<16;r++) acc[r] += x[(size_t)(n0+r)*DM + j];  // residual
  for (int r=0;r<16;r++){
    const float v = acc[r];
    float s1=v, s2=v*v;
    #pragma unroll
    for (int o=32;o>0;o>>=1){ s1+=__shfl_down(s1,o); s2+=__shfl_down(s2,o); }
    if ((j&63)==0){ red[j>>6]=s1; red[4+(j>>6)]=s2; }
    __syncthreads();
    const float fs1 = red[0]+red[1]+red[2]+red[3];
    const float fs2 = red[4]+red[5]+red[6]+red[7];
    const float mu  = fs1*(1.0f/256.0f);
    const float var = fs2*(1.0f/256.0f) - mu*mu;
    const float ov  = (v-mu)*rsqrtf(var+1e-5f)*lw + lb;
    out[(size_t)(n0+r)*DM + j] = ov;
    __syncthreads();
  }
}

extern "C" void kernel_launch(void* const* d_in, const int* in_sizes, int n_in,
                              void* d_out, int out_size, void* d_ws, size_t ws_size,
                              hipStream_t stream) {
  const float* x   = (const float*)d_in[0];
  const int*   ei  = (const int*  )d_in[1];
  const float* Wq  = (const float*)d_in[2];
  const float* bq  = (const float*)d_in[3];
  const float* Wk  = (const float*)d_in[4];
  const float* bk  = (const float*)d_in[5];
  const float* Wv  = (const float*)d_in[6];
  const float* bv  = (const float*)d_in[7];
  const float* Wo  = (const float*)d_in[8];
  const float* bo  = (const float*)d_in[9];
  const float* lnw = (const float*)d_in[10];
  const float* lnb = (const float*)d_in[11];

  char* ws = (char*)d_ws;
  u64t*  A   = (u64t*)(ws);                      // 2 MiB adjacency bits
  u64t*  M   = (u64t*)(ws + (2u<<20));           // 2 MiB reach-2 bits
  u16t*  Qh  = (u16t*)(ws + (4u<<20));           // 2 MiB bf16 [h][n][32] (scaled)
  u16t*  Kh  = (u16t*)(ws + (6u<<20));           // 2 MiB bf16 [h][n][32]
  u16t*  Vth = (u16t*)(ws + (8u<<20));           // 2 MiB bf16 [h][32][n]
  float* att = (float*)(ws + (10u<<20));         // 4 MiB fp32

  hipMemsetAsync(A, 0, (2u<<20), stream);
  edges_kernel<<<NE/256, 256, 0, stream>>>(ei, A);
  reach2_kernel<<<NN, 256, 0, stream>>>(A, M);
  qkv_kernel<<<NN/16, 256, 0, stream>>>(x, Wq,bq, Wk,bk, Wv,bv, Qh, Kh, Vth);
  dim3 ag(NN/64, NH);
  fattn_kernel<<<ag, 256, 0, stream>>>(M, Qh, Kh, Vth, att);
  outln_kernel<<<NN/16, 256, 0, stream>>>(att, Wo, bo, x, lnw, lnb, (float*)d_out);
}

// Round 4
// 255.579 us; speedup vs baseline: 8.5371x; 1.1782x over previous
//
#include <hip/hip_runtime.h>
#include <math.h>

#define NN   4096
#define DM   256
#define NH   8
#define HDIM 32
#define NE   65536
#define ROWW 64   // u64 words per 4096-bit mask row

typedef unsigned short u16t;
typedef unsigned int   u32t;
typedef unsigned long long u64t;
typedef __attribute__((ext_vector_type(8))) short bf16x8;
typedef __attribute__((ext_vector_type(4))) float f32x4;

__device__ __forceinline__ u16t f2bf(float f){            // RNE
  u32t x; __builtin_memcpy(&x,&f,4);
  u32t r=(x+0x7fffu+((x>>16)&1u))>>16;
  return (u16t)r;
}
__device__ __forceinline__ u16t f2bf_fast(float f){       // round-half-up (p>=0)
  u32t x; __builtin_memcpy(&x,&f,4);
  return (u16t)((x+0x8000u)>>16);
}
__device__ __forceinline__ float fexp2(float x){
#if __has_builtin(__builtin_amdgcn_exp2f)
  return __builtin_amdgcn_exp2f(x);
#else
  return exp2f(x);
#endif
}

// async global->LDS, 16B per lane; lds dst is wave-uniform base (+lane*16 by HW)
__device__ __forceinline__ void gl2lds16(const void* g, void* l){
  auto gp = (const __attribute__((address_space(1))) u32t*)(unsigned long long)g;
  auto lp = (__attribute__((address_space(3))) u32t*)(u32t)(unsigned long long)l;
  __builtin_amdgcn_global_load_lds(gp, lp, 16, 0, 0);
}

// ---------------- mask build ----------------
__global__ __launch_bounds__(256) void edges_kernel(const int* __restrict__ ei, u64t* __restrict__ A){
  int e = blockIdx.x*256 + threadIdx.x;
  if (e < NE){
    int s = ei[e];
    int d = ei[NE + e];
    atomicOr(&A[(size_t)s*ROWW + (d>>6)], 1ull<<(d&63));
    atomicOr(&A[(size_t)d*ROWW + (s>>6)], 1ull<<(s&63));
  }
  if (e < NN){
    atomicOr(&A[(size_t)e*ROWW + (e>>6)], 1ull<<(e&63));
  }
}

__global__ __launch_bounds__(256) void reach2_kernel(const u64t* __restrict__ A, u64t* __restrict__ M){
  __shared__ u16t list[NN];
  __shared__ int  cnt;
  __shared__ u64t accs[256];
  const int tid = threadIdx.x;
  const int n   = blockIdx.x;
  const int t = tid & 63;
  const int g = tid >> 6;
  if (tid==0) cnt=0;
  __syncthreads();
  if (tid < ROWW){
    u64t w = A[(size_t)n*ROWW + tid];
    int base = tid*64;
    while (w){
      int b = __builtin_ctzll(w);
      w &= w-1;
      int i = atomicAdd(&cnt,1);
      list[i] = (u16t)(base+b);
    }
  }
  __syncthreads();
  const int c = cnt;
  u64t acc = 0;
  for (int i=g; i<c; i+=4){
    acc |= A[(size_t)list[i]*ROWW + t];
  }
  accs[tid] = acc;
  __syncthreads();
  if (tid < ROWW){
    u64t a = accs[tid] | accs[64+tid] | accs[128+tid] | accs[192+tid];
    M[(size_t)n*ROWW + tid] = a;
  }
}

// ---------------- QKV projection ----------------
// Q bf16 [h][n][32] pre-scaled by log2(e)/sqrt(32); K bf16 [h][n][32]; V^T bf16 [h][32][n].
__global__ __launch_bounds__(256) void qkv_kernel(const float* __restrict__ x,
    const float* __restrict__ Wq, const float* __restrict__ bq,
    const float* __restrict__ Wk, const float* __restrict__ bk,
    const float* __restrict__ Wv, const float* __restrict__ bv,
    u16t* __restrict__ Qh, u16t* __restrict__ Kh, u16t* __restrict__ Vth)
{
  __shared__ __align__(16) float Xs[16*DM];
  const int j  = threadIdx.x;
  const int n0 = blockIdx.x*16;
  #pragma unroll
  for (int r=0;r<16;r++) Xs[r*DM+j] = x[(size_t)(n0+r)*DM + j];
  __syncthreads();
  float aq[16], ak[16], av[16];
  const float bqv=bq[j], bkv=bk[j], bvv=bv[j];
  #pragma unroll
  for (int r=0;r<16;r++){ aq[r]=bqv; ak[r]=bkv; av[r]=bvv; }
  for (int k=0;k<DM;k+=4){
    const float wq0=Wq[(k+0)*DM+j], wq1=Wq[(k+1)*DM+j], wq2=Wq[(k+2)*DM+j], wq3=Wq[(k+3)*DM+j];
    const float wk0=Wk[(k+0)*DM+j], wk1=Wk[(k+1)*DM+j], wk2=Wk[(k+2)*DM+j], wk3=Wk[(k+3)*DM+j];
    const float wv0=Wv[(k+0)*DM+j], wv1=Wv[(k+1)*DM+j], wv2=Wv[(k+2)*DM+j], wv3=Wv[(k+3)*DM+j];
    #pragma unroll
    for (int r=0;r<16;r++){
      float4 a = *(const float4*)&Xs[r*DM+k];
      aq[r] += a.x*wq0 + a.y*wq1 + a.z*wq2 + a.w*wq3;
      ak[r] += a.x*wk0 + a.y*wk1 + a.z*wk2 + a.w*wk3;
      av[r] += a.x*wv0 + a.y*wv1 + a.z*wv2 + a.w*wv3;
    }
  }
  // qs = 1/sqrt(32) * log2(e)  (fattn uses exp2 directly)
  const float qs = 0.25503473f;
  const int h = j>>5, d = j&31;
  #pragma unroll
  for (int r=0;r<16;r++){
    const int n = n0+r;
    Qh[((size_t)h*NN + n)*HDIM + d] = f2bf(aq[r]*qs);
    Kh[((size_t)h*NN + n)*HDIM + d] = f2bf(ak[r]);
  }
  // V^T: thread j (=h*32+d) owns output row j, cols n0..n0+15 — pack & store 32B
  u32t vp[8];
  #pragma unroll
  for (int i=0;i<8;i++) vp[i] = (u32t)f2bf(av[2*i]) | ((u32t)f2bf(av[2*i+1])<<16);
  u16t* vo = Vth + (size_t)j*NN + n0;
  *(uint4*)(vo)     = make_uint4(vp[0],vp[1],vp[2],vp[3]);
  *(uint4*)(vo+8)   = make_uint4(vp[4],vp[5],vp[6],vp[7]);
}

// ---------------- dense flash attention (MFMA, no-max softmax) ----------------
// 1-D grid 512: h = bx&7 (head==XCD for L2 locality), qt = bx>>3.
// 256 threads = 4 waves, wave owns 16 q-rows.
__global__ __launch_bounds__(256) void fattn_kernel(
    const u64t* __restrict__ M, const u16t* __restrict__ Qh,
    const u16t* __restrict__ Kh, const u16t* __restrict__ Vth,
    float* __restrict__ att)
{
  __shared__ __align__(16) u16t Ks[2][64*HDIM];   // K tile, swizzled chunks
  __shared__ __align__(16) u16t Vs[2][HDIM*64];   // V^T tile [d][key], swizzled
  __shared__ __align__(16) u64t Ms[2][64];        // mask word per q-row
  __shared__ __align__(16) u16t Ps[4][16*64];     // per-wave P (C->A layout hop), swizzled

  const int tid  = threadIdx.x;
  const int w    = tid >> 6;
  const int lane = tid & 63;
  const int l15  = lane & 15;
  const int quad = lane >> 4;
  const int h    = blockIdx.x & 7;
  const int n0   = (blockIdx.x >> 3) * 64;

  const u16t* Kg = Kh  + (size_t)h*NN*HDIM;
  const u16t* Vg = Vth + (size_t)h*HDIM*NN;
  // staging inverse-swizzle offsets (phys chunk = tid -> logical global chunk)
  const int kr = tid>>2, kqp = tid&3;
  const int kgo = kr*HDIM + (kqp ^ ((kr>>1)&3))*8;   // + kt*2048
  const int vr = tid>>3, vqp = tid&7;
  const int vgo = vr*NN + (vqp ^ (vr&7))*8;          // + kt*64

  // Q A-fragment (rows w*16+l15, k-chunk quad*8..+7)
  bf16x8 qfrag;
  {
    const u16t* qp = Qh + ((size_t)h*NN + (n0 + w*16 + l15))*HDIM + quad*8;
    uint4 t = *(const uint4*)qp;
    __builtin_memcpy(&qfrag, &t, 16);
  }

  float lrow[4] = {0.f,0.f,0.f,0.f};
  f32x4 Oacc[2] = {{0.f,0.f,0.f,0.f},{0.f,0.f,0.f,0.f}};
  const f32x4 zero = {0.f,0.f,0.f,0.f};

  #define STAGE(kt, buf) do { \
    gl2lds16(Kg + (size_t)(kt)*2048 + kgo, &Ks[(buf)][w*512]); \
    gl2lds16(Vg + (size_t)(kt)*64 + vgo,  &Vs[(buf)][w*512]); \
    if (tid < 64) Ms[(buf)][tid] = M[(size_t)(n0+tid)*ROWW + (kt)]; \
  } while(0)

  STAGE(0, 0);
  const int kswz = (l15>>1)&3;
  const int pswz = l15&7;

  for (int kt=0; kt<64; ++kt){
    __syncthreads();                       // drains staging (vmcnt) + orders buffers
    if (kt < 63) STAGE(kt+1, (kt+1)&1);
    const int buf = kt&1;

    // S = Q K^T : 4 MFMAs (key groups of 16); S already in log2 domain
    f32x4 S[4];
    #pragma unroll
    for (int g=0; g<4; ++g){
      const u16t* kp = &Ks[buf][(g*16+l15)*HDIM + (quad ^ kswz)*8];
      uint4 t = *(const uint4*)kp;
      bf16x8 kb; __builtin_memcpy(&kb,&t,16);
      S[g] = __builtin_amdgcn_mfma_f32_16x16x32_bf16(qfrag, kb, zero, 0,0,0);
    }

    // p = exp2(S) zeroed where masked; accumulate row sums (no max tracking)
    u64t sh[4];
    #pragma unroll
    for (int r=0;r<4;r++) sh[r] = Ms[buf][quad*4+r] >> l15;
    #pragma unroll
    for (int g=0; g<4; ++g){
      #pragma unroll
      for (int r=0;r<4;r++){
        float p = fexp2(S[g][r]);
        p = ((sh[r] >> (g*16)) & 1ull) ? p : 0.f;
        S[g][r] = p;
        lrow[r] += p;
      }
    }

    // P: C-layout -> LDS (bf16, swizzled) -> A-layout
    #pragma unroll
    for (int g=0; g<4; ++g){
      const int ch = g*2 + (l15>>3);
      #pragma unroll
      for (int r=0;r<4;r++){
        const int pr = quad*4+r;
        Ps[w][pr*64 + (ch ^ (pr&7))*8 + (l15&7)] = f2bf_fast(S[g][r]);
      }
    }

    // O += P V : 2 key-chunks x 2 d-halves
    #pragma unroll
    for (int kc=0; kc<2; ++kc){
      const u16t* pp = &Ps[w][l15*64 + ((kc*4+quad) ^ pswz)*8];
      uint4 ta = *(const uint4*)pp;
      bf16x8 pa; __builtin_memcpy(&pa,&ta,16);
      #pragma unroll
      for (int dh=0; dh<2; ++dh){
        const u16t* vp = &Vs[buf][(dh*16+l15)*64 + ((kc*4+quad) ^ pswz)*8];
        uint4 tb = *(const uint4*)vp;
        bf16x8 vb; __builtin_memcpy(&vb,&tb,16);
        Oacc[dh] = __builtin_amdgcn_mfma_f32_16x16x32_bf16(pa, vb, Oacc[dh], 0,0,0);
      }
    }
  }
  #undef STAGE

  // epilogue: reduce l across the quad's 16 lanes, then O/l -> att fp32
  #pragma unroll
  for (int r=0;r<4;r++){
    float l = lrow[r];
    l += __shfl_xor(l,1); l += __shfl_xor(l,2); l += __shfl_xor(l,4); l += __shfl_xor(l,8);
    const float inv = 1.f/l;
    const int n = n0 + w*16 + quad*4 + r;
    float* op = att + (size_t)n*DM + h*HDIM;
    op[l15]    = Oacc[0][r]*inv;
    op[16+l15] = Oacc[1][r]*inv;
  }
}

// ---------------- output projection + residual + layernorm ----------------
__global__ __launch_bounds__(256) void outln_kernel(const float* __restrict__ att,
    const float* __restrict__ Wo, const float* __restrict__ bo,
    const float* __restrict__ x, const float* __restrict__ lnw, const float* __restrict__ lnb,
    float* __restrict__ out)
{
  __shared__ __align__(16) float As[16*DM];
  __shared__ float red[8];
  const int j  = threadIdx.x;
  const int n0 = blockIdx.x*16;
  #pragma unroll
  for (int r=0;r<16;r++) As[r*DM+j] = att[(size_t)(n0+r)*DM + j];
  __syncthreads();
  float acc[16];
  const float bov = bo[j];
  #pragma unroll
  for (int r=0;r<16;r++) acc[r]=bov;
  for (int k=0;k<DM;k+=4){
    const float w0=Wo[(k+0)*DM+j];
    const float w1=Wo[(k+1)*DM+j];
    const float w2=Wo[(k+2)*DM+j];
    const float w3=Wo[(k+3)*DM+j];
    #pragma unroll
    for (int r=0;r<16;r++){
      float4 a = *(const float4*)&As[r*DM+k];
      acc[r] += a.x*w0 + a.y*w1 + a.z*w2 + a.w*w3;
    }
  }
  const float lw=lnw[j], lb=lnb[j];
  #pragma unroll
  for (int r=0;r<16;r++) acc[r] += x[(size_t)(n0+r)*DM + j];  // residual
  for (int r=0;r<16;r++){
    const float v = acc[r];
    float s1=v, s2=v*v;
    #pragma unroll
    for (int o=32;o>0;o>>=1){ s1+=__shfl_down(s1,o); s2+=__shfl_down(s2,o); }
    if ((j&63)==0){ red[j>>6]=s1; red[4+(j>>6)]=s2; }
    __syncthreads();
    const float fs1 = red[0]+red[1]+red[2]+red[3];
    const float fs2 = red[4]+red[5]+red[6]+red[7];
    const float mu  = fs1*(1.0f/256.0f);
    const float var = fs2*(1.0f/256.0f) - mu*mu;
    const float ov  = (v-mu)*rsqrtf(var+1e-5f)*lw + lb;
    out[(size_t)(n0+r)*DM + j] = ov;
    __syncthreads();
  }
}

extern "C" void kernel_launch(void* const* d_in, const int* in_sizes, int n_in,
                              void* d_out, int out_size, void* d_ws, size_t ws_size,
                              hipStream_t stream) {
  const float* x   = (const float*)d_in[0];
  const int*   ei  = (const int*  )d_in[1];
  const float* Wq  = (const float*)d_in[2];
  const float* bq  = (const float*)d_in[3];
  const float* Wk  = (const float*)d_in[4];
  const float* bk  = (const float*)d_in[5];
  const float* Wv  = (const float*)d_in[6];
  const float* bv  = (const float*)d_in[7];
  const float* Wo  = (const float*)d_in[8];
  const float* bo  = (const float*)d_in[9];
  const float* lnw = (const float*)d_in[10];
  const float* lnb = (const float*)d_in[11];

  char* ws = (char*)d_ws;
  u64t*  A   = (u64t*)(ws);                      // 2 MiB adjacency bits
  u64t*  M   = (u64t*)(ws + (2u<<20));           // 2 MiB reach-2 bits
  u16t*  Qh  = (u16t*)(ws + (4u<<20));           // 2 MiB bf16 [h][n][32] (scaled)
  u16t*  Kh  = (u16t*)(ws + (6u<<20));           // 2 MiB bf16 [h][n][32]
  u16t*  Vth = (u16t*)(ws + (8u<<20));           // 2 MiB bf16 [h][32][n]
  float* att = (float*)(ws + (10u<<20));         // 4 MiB fp32

  hipMemsetAsync(A, 0, (2u<<20), stream);
  edges_kernel<<<NE/256, 256, 0, stream>>>(ei, A);
  reach2_kernel<<<NN, 256, 0, stream>>>(A, M);
  qkv_kernel<<<NN/16, 256, 0, stream>>>(x, Wq,bq, Wk,bk, Wv,bv, Qh, Kh, Vth);
  fattn_kernel<<<512, 256, 0, stream>>>(M, Qh, Kh, Vth, att);
  outln_kernel<<<NN/16, 256, 0, stream>>>(att, Wo, bo, x, lnw, lnb, (float*)d_out);
}

// Round 5
// 190.608 us; speedup vs baseline: 11.4471x; 1.3409x over previous
//
#include <hip/hip_runtime.h>
#include <math.h>

#define NN   4096
#define DM   256
#define NH   8
#define HDIM 32
#define NE   65536
#define ROWW 64
#define QS   0.25503473f   // log2(e)/sqrt(32)

typedef unsigned short u16t;
typedef unsigned int   u32t;
typedef unsigned long long u64t;
typedef __attribute__((ext_vector_type(8))) short bf16x8;
typedef __attribute__((ext_vector_type(4))) float f32x4;

__device__ __forceinline__ u16t f2bf(float f){            // RNE
  u32t x; __builtin_memcpy(&x,&f,4);
  u32t r=(x+0x7fffu+((x>>16)&1u))>>16;
  return (u16t)r;
}
__device__ __forceinline__ u16t f2bf_fast(float f){       // round-half-up (p>=0)
  u32t x; __builtin_memcpy(&x,&f,4);
  return (u16t)((x+0x8000u)>>16);
}
__device__ __forceinline__ float fexp2(float x){
#if __has_builtin(__builtin_amdgcn_exp2f)
  return __builtin_amdgcn_exp2f(x);
#else
  return exp2f(x);
#endif
}
__device__ __forceinline__ void gl2lds16(const void* g, void* l){
  auto gp = (const __attribute__((address_space(1))) u32t*)(unsigned long long)g;
  auto lp = (__attribute__((address_space(3))) u32t*)(u32t)(unsigned long long)l;
  __builtin_amdgcn_global_load_lds(gp, lp, 16, 0, 0);
}

// ---------------- mask build ----------------
__global__ __launch_bounds__(256) void edges_kernel(const int* __restrict__ ei, u64t* __restrict__ A){
  int e = blockIdx.x*256 + threadIdx.x;
  if (e < NE){
    int s = ei[e];
    int d = ei[NE + e];
    atomicOr(&A[(size_t)s*ROWW + (d>>6)], 1ull<<(d&63));
    atomicOr(&A[(size_t)d*ROWW + (s>>6)], 1ull<<(s&63));
  }
  if (e < NN){
    atomicOr(&A[(size_t)e*ROWW + (e>>6)], 1ull<<(e&63));
  }
}

__global__ __launch_bounds__(256) void reach2_kernel(const u64t* __restrict__ A, u64t* __restrict__ M){
  __shared__ u16t list[NN];
  __shared__ int  cnt;
  __shared__ u64t accs[256];
  const int tid = threadIdx.x;
  const int n   = blockIdx.x;
  const int t = tid & 63;
  const int g = tid >> 6;
  if (tid==0) cnt=0;
  __syncthreads();
  if (tid < ROWW){
    u64t w = A[(size_t)n*ROWW + tid];
    int base = tid*64;
    while (w){
      int b = __builtin_ctzll(w);
      w &= w-1;
      int i = atomicAdd(&cnt,1);
      list[i] = (u16t)(base+b);
    }
  }
  __syncthreads();
  const int c = cnt;
  u64t acc = 0;
  for (int i=g; i<c; i+=4){
    acc |= A[(size_t)list[i]*ROWW + t];
  }
  accs[tid] = acc;
  __syncthreads();
  if (tid < ROWW){
    u64t a = accs[tid] | accs[64+tid] | accs[128+tid] | accs[192+tid];
    M[(size_t)n*ROWW + tid] = a;
  }
}

// ---------------- conversions: W transpose->bf16 (Q scaled), bias fuse, x->bf16 ----------------
// grid 113: b 0..47 = W tiles (3 mats x 16), b 48 = bias, b 49..112 = x convert
__global__ __launch_bounds__(256) void conv_kernel(
    const float* __restrict__ Wq, const float* __restrict__ bq,
    const float* __restrict__ Wk, const float* __restrict__ bk,
    const float* __restrict__ Wv, const float* __restrict__ bv,
    const float* __restrict__ x,
    u16t* __restrict__ Wtb, float* __restrict__ bb, u16t* __restrict__ xb)
{
  const int b = blockIdx.x, tid = threadIdx.x;
  if (b < 48){
    __shared__ __align__(16) float Tf[64*64];
    const int mat = b/16, t = b%16;
    const int k0 = (t>>2)*64, nc0 = (t&3)*64;
    const float* W = mat==0? Wq : (mat==1? Wk : Wv);
    const float scale = (mat==0) ? QS : 1.0f;
    #pragma unroll
    for (int i=0;i<4;i++){
      int c = i*256+tid;
      int kk = c>>4, ch = c&15;
      float4 v = *(const float4*)(W + (size_t)(k0+kk)*256 + nc0 + ch*4);
      *(float4*)&Tf[kk*64 + ch*4] = v;
    }
    __syncthreads();
    const int nn = tid>>2, kc = tid&3;
    u32t pk[8];
    #pragma unroll
    for (int p=0;p<8;p++){
      float a  = Tf[(kc*16+2*p  )*64 + nn]*scale;
      float b2 = Tf[(kc*16+2*p+1)*64 + nn]*scale;
      pk[p] = (u32t)f2bf(a) | ((u32t)f2bf(b2)<<16);
    }
    u16t* o = Wtb + ((size_t)mat*256 + nc0 + nn)*256 + k0 + kc*16;
    *(uint4*)o     = make_uint4(pk[0],pk[1],pk[2],pk[3]);
    *(uint4*)(o+8) = make_uint4(pk[4],pk[5],pk[6],pk[7]);
  } else if (b == 48){
    #pragma unroll
    for (int i=0;i<3;i++){
      int j = i*256 + tid;
      bb[j] = (j<256) ? bq[j]*QS : ((j<512) ? bk[j-256] : bv[j-512]);
    }
  } else {
    const int bi = b-49;
    #pragma unroll
    for (int i=0;i<16;i++){
      int idx = (bi*256+tid) + i*16384;   // float4 chunks, 262144 total
      float4 v = *(const float4*)(x + (size_t)idx*4);
      u32t p0 = (u32t)f2bf(v.x) | ((u32t)f2bf(v.y)<<16);
      u32t p1 = (u32t)f2bf(v.z) | ((u32t)f2bf(v.w)<<16);
      *(uint2*)(xb + (size_t)idx*4) = make_uint2(p0,p1);
    }
  }
}

// ---------------- fused QKV GEMM: QKV[4096][768] = xb @ Wtb^T + bb (bf16 in, fp32 acc) ----------------
// 64M x 64N per block, K=256 staged in LDS (swizzled); B-frags streamed from L2.
__global__ __launch_bounds__(256) void gemm_kernel(
    const u16t* __restrict__ xb, const u16t* __restrict__ Wtb,
    const float* __restrict__ bb, u16t* __restrict__ QKV)
{
  __shared__ __align__(16) u16t Xs[64*256];
  const int tid = threadIdx.x;
  const int w = tid>>6, lane = tid&63, l15 = lane&15, quad = lane>>4;
  const int mt = blockIdx.x / 12;
  const int nt = blockIdx.x % 12;
  const int m0 = mt*64, n0 = nt*64;
  #pragma unroll
  for (int i=0;i<8;i++){
    int c = i*256 + tid;
    int row = c>>5, pc = c&31;
    int lc = pc ^ (row&7);
    gl2lds16(xb + (size_t)(m0+row)*256 + lc*8, &Xs[(size_t)(i*256 + w*64)*8]);
  }
  __syncthreads();
  bf16x8 afr[8];
  {
    const int row = w*16 + l15;
    #pragma unroll
    for (int kc=0;kc<8;kc++){
      const int phys = (kc*4+quad) ^ (row&7);
      uint4 t = *(const uint4*)&Xs[row*256 + phys*8];
      __builtin_memcpy(&afr[kc], &t, 16);
    }
  }
  f32x4 acc[4];
  #pragma unroll
  for (int nf=0;nf<4;nf++){
    float b2 = bb[n0 + nf*16 + l15];
    acc[nf] = (f32x4){b2,b2,b2,b2};
  }
  #pragma unroll
  for (int nf=0;nf<4;nf++){
    const u16t* Bp = Wtb + (size_t)(n0 + nf*16 + l15)*256 + quad*8;
    #pragma unroll
    for (int kc=0;kc<8;kc++){
      uint4 t = *(const uint4*)(Bp + kc*32);
      bf16x8 bfr; __builtin_memcpy(&bfr,&t,16);
      acc[nf] = __builtin_amdgcn_mfma_f32_16x16x32_bf16(afr[kc], bfr, acc[nf], 0,0,0);
    }
  }
  #pragma unroll
  for (int nf=0;nf<4;nf++){
    const int col = n0 + nf*16 + l15;
    #pragma unroll
    for (int r=0;r<4;r++){
      const int m = m0 + w*16 + quad*4 + r;
      QKV[(size_t)m*768 + col] = f2bf(acc[nf][r]);
    }
  }
}

// ---------------- V transpose: QKV cols 512..767 -> Vth[256][4096] ----------------
__global__ __launch_bounds__(256) void vtrans_kernel(const u16t* __restrict__ QKV, u16t* __restrict__ Vth){
  __shared__ u16t Ts[64*256];
  const int tid = threadIdx.x;
  const int n0 = blockIdx.x*64;
  #pragma unroll
  for (int i=0;i<8;i++){
    int c = i*256+tid;
    int n = c>>5, ch = c&31;
    uint4 v = *(const uint4*)(QKV + (size_t)(n0+n)*768 + 512 + ch*8);
    *(uint4*)&Ts[n*256 + ch*8] = v;
  }
  __syncthreads();
  u32t pk[32];
  #pragma unroll
  for (int p=0;p<32;p++){
    u16t a = Ts[(2*p  )*256 + tid];
    u16t b = Ts[(2*p+1)*256 + tid];
    pk[p] = (u32t)a | ((u32t)b<<16);
  }
  u16t* o = Vth + (size_t)tid*NN + n0;
  #pragma unroll
  for (int q=0;q<8;q++)
    *(uint4*)(o + q*8) = make_uint4(pk[q*4],pk[q*4+1],pk[q*4+2],pk[q*4+3]);
}

// ---------------- dense flash attention (MFMA, no-max softmax, key-split x2) ----------------
// grid 1024: h = bx&7, qt = (bx>>3)&63, half = bx>>9. Each block: 32 key-tiles.
// Writes unnormalized O partial + L partial; outln merges.
__global__ __launch_bounds__(256) void fattn_kernel(
    const u64t* __restrict__ M, const u16t* __restrict__ QKV,
    const u16t* __restrict__ Vth,
    float* __restrict__ attP, float* __restrict__ Lp)
{
  __shared__ __align__(16) u16t Ks[2][64*HDIM];
  __shared__ __align__(16) u16t Vs[2][HDIM*64];
  __shared__ __align__(16) u64t Ms[2][64];
  __shared__ __align__(16) u16t Ps[4][16*64];

  const int tid  = threadIdx.x;
  const int w    = tid >> 6;
  const int lane = tid & 63;
  const int l15  = lane & 15;
  const int quad = lane >> 4;
  const int h    = blockIdx.x & 7;
  const int n0   = ((blockIdx.x >> 3) & 63) * 64;
  const int half = blockIdx.x >> 9;
  const int k0   = half * 32;

  const u16t* Kg = QKV + 256 + h*HDIM;          // row-major stride 768
  const u16t* Vg = Vth + (size_t)h*HDIM*NN;
  const int kr = tid>>2, kqp = tid&3;
  const int kgo = kr*768 + (kqp ^ ((kr>>1)&3))*8;
  const int vr = tid>>3, vqp = tid&7;
  const int vgo = vr*NN + (vqp ^ (vr&7))*8;

  bf16x8 qfrag;
  {
    const u16t* qp = QKV + (size_t)(n0 + w*16 + l15)*768 + h*HDIM + quad*8;
    uint4 t = *(const uint4*)qp;
    __builtin_memcpy(&qfrag, &t, 16);
  }

  float lrow[4] = {0.f,0.f,0.f,0.f};
  f32x4 Oacc[2] = {{0.f,0.f,0.f,0.f},{0.f,0.f,0.f,0.f}};
  const f32x4 zero = {0.f,0.f,0.f,0.f};

  #define STAGE(kt, buf) do { \
    gl2lds16(Kg + (size_t)(kt)*64*768 + kgo, &Ks[(buf)][w*512]); \
    gl2lds16(Vg + (size_t)(kt)*64 + vgo,  &Vs[(buf)][w*512]); \
    if (tid < 64) Ms[(buf)][tid] = M[(size_t)(n0+tid)*ROWW + (kt)]; \
  } while(0)

  STAGE(k0, 0);
  const int kswz = (l15>>1)&3;
  const int pswz = l15&7;

  for (int ti=0; ti<32; ++ti){
    __syncthreads();
    if (ti < 31) STAGE(k0+ti+1, (ti+1)&1);
    const int buf = ti&1;

    f32x4 S[4];
    #pragma unroll
    for (int g=0; g<4; ++g){
      const u16t* kp = &Ks[buf][(g*16+l15)*HDIM + (quad ^ kswz)*8];
      uint4 t = *(const uint4*)kp;
      bf16x8 kb; __builtin_memcpy(&kb,&t,16);
      S[g] = __builtin_amdgcn_mfma_f32_16x16x32_bf16(qfrag, kb, zero, 0,0,0);
    }

    u64t sh[4];
    #pragma unroll
    for (int r=0;r<4;r++) sh[r] = Ms[buf][quad*4+r] >> l15;
    #pragma unroll
    for (int g=0; g<4; ++g){
      #pragma unroll
      for (int r=0;r<4;r++){
        float p = fexp2(S[g][r]);
        p = ((sh[r] >> (g*16)) & 1ull) ? p : 0.f;
        S[g][r] = p;
        lrow[r] += p;
      }
    }

    #pragma unroll
    for (int g=0; g<4; ++g){
      const int ch = g*2 + (l15>>3);
      #pragma unroll
      for (int r=0;r<4;r++){
        const int pr = quad*4+r;
        Ps[w][pr*64 + (ch ^ (pr&7))*8 + (l15&7)] = f2bf_fast(S[g][r]);
      }
    }

    #pragma unroll
    for (int kc=0; kc<2; ++kc){
      const u16t* pp = &Ps[w][l15*64 + ((kc*4+quad) ^ pswz)*8];
      uint4 ta = *(const uint4*)pp;
      bf16x8 pa; __builtin_memcpy(&pa,&ta,16);
      #pragma unroll
      for (int dh=0; dh<2; ++dh){
        const u16t* vp = &Vs[buf][(dh*16+l15)*64 + ((kc*4+quad) ^ pswz)*8];
        uint4 tb = *(const uint4*)vp;
        bf16x8 vb; __builtin_memcpy(&vb,&tb,16);
        Oacc[dh] = __builtin_amdgcn_mfma_f32_16x16x32_bf16(pa, vb, Oacc[dh], 0,0,0);
      }
    }
  }
  #undef STAGE

  // epilogue: store raw O partial + L partial
  #pragma unroll
  for (int r=0;r<4;r++){
    float l = lrow[r];
    l += __shfl_xor(l,1); l += __shfl_xor(l,2); l += __shfl_xor(l,4); l += __shfl_xor(l,8);
    const int n = n0 + w*16 + quad*4 + r;
    if (l15 == 0) Lp[(size_t)half*NH*NN + (size_t)h*NN + n] = l;
    float* op = attP + ((size_t)half*NN + n)*DM + h*HDIM;
    op[l15]    = Oacc[0][r];
    op[16+l15] = Oacc[1][r];
  }
}

// ---------------- merge halves + output projection + residual + layernorm ----------------
__global__ __launch_bounds__(256) void outln_kernel(
    const float* __restrict__ attP, const float* __restrict__ Lp,
    const float* __restrict__ Wo, const float* __restrict__ bo,
    const float* __restrict__ x, const float* __restrict__ lnw, const float* __restrict__ lnb,
    float* __restrict__ out)
{
  __shared__ __align__(16) float As[8*DM];
  __shared__ float red[8];
  const int j  = threadIdx.x;
  const int n0 = blockIdx.x*8;
  const int h  = j>>5;
  #pragma unroll
  for (int r=0;r<8;r++){
    const int n = n0+r;
    float a0 = attP[(size_t)n*DM + j];
    float a1 = attP[(size_t)(NN + n)*DM + j];
    float l  = Lp[(size_t)h*NN + n] + Lp[(size_t)NH*NN + (size_t)h*NN + n];
    As[r*DM+j] = (a0+a1)/l;
  }
  __syncthreads();
  float acc[8];
  const float bov = bo[j];
  #pragma unroll
  for (int r=0;r<8;r++) acc[r]=bov;
  for (int k=0;k<DM;k+=4){
    const float w0=Wo[(k+0)*DM+j];
    const float w1=Wo[(k+1)*DM+j];
    const float w2=Wo[(k+2)*DM+j];
    const float w3=Wo[(k+3)*DM+j];
    #pragma unroll
    for (int r=0;r<8;r++){
      float4 a = *(const float4*)&As[r*DM+k];
      acc[r] += a.x*w0 + a.y*w1 + a.z*w2 + a.w*w3;
    }
  }
  const float lw=lnw[j], lb=lnb[j];
  #pragma unroll
  for (int r=0;r<8;r++) acc[r] += x[(size_t)(n0+r)*DM + j];  // residual
  for (int r=0;r<8;r++){
    const float v = acc[r];
    float s1=v, s2=v*v;
    #pragma unroll
    for (int o=32;o>0;o>>=1){ s1+=__shfl_down(s1,o); s2+=__shfl_down(s2,o); }
    if ((j&63)==0){ red[j>>6]=s1; red[4+(j>>6)]=s2; }
    __syncthreads();
    const float fs1 = red[0]+red[1]+red[2]+red[3];
    const float fs2 = red[4]+red[5]+red[6]+red[7];
    const float mu  = fs1*(1.0f/256.0f);
    const float var = fs2*(1.0f/256.0f) - mu*mu;
    const float ov  = (v-mu)*rsqrtf(var+1e-5f)*lw + lb;
    out[(size_t)(n0+r)*DM + j] = ov;
    __syncthreads();
  }
}

extern "C" void kernel_launch(void* const* d_in, const int* in_sizes, int n_in,
                              void* d_out, int out_size, void* d_ws, size_t ws_size,
                              hipStream_t stream) {
  const float* x   = (const float*)d_in[0];
  const int*   ei  = (const int*  )d_in[1];
  const float* Wq  = (const float*)d_in[2];
  const float* bq  = (const float*)d_in[3];
  const float* Wk  = (const float*)d_in[4];
  const float* bk  = (const float*)d_in[5];
  const float* Wv  = (const float*)d_in[6];
  const float* bv  = (const float*)d_in[7];
  const float* Wo  = (const float*)d_in[8];
  const float* bo  = (const float*)d_in[9];
  const float* lnw = (const float*)d_in[10];
  const float* lnb = (const float*)d_in[11];

  char* ws = (char*)d_ws;
  u64t*  A    = (u64t*)(ws);                     // 0..2MB adjacency bits
  u64t*  M    = (u64t*)(ws + (2u<<20));          // 2..4MB reach-2 bits
  u16t*  xb   = (u16t*)(ws + (4u<<20));          // 4..6MB x bf16 (dead after gemm)
  u16t*  Wtb  = (u16t*)(ws + (6u<<20));          // 6..6.4MB W^T bf16 (dead after gemm)
  float* bb   = (float*)(ws + (6800u<<10));      // ~6.65MB bias fp32 (dead after gemm)
  float* attP = (float*)(ws + (4u<<20));         // 4..12MB O partials (aliases xb/Wtb/bb, written after)
  u16t*  QKV  = (u16t*)(ws + (12u<<20));         // 12..18MB fused QKV bf16 [4096][768]
  u16t*  Vth  = (u16t*)(ws + (18u<<20));         // 18..20MB V^T bf16 [256][4096]
  float* Lp   = (float*)(ws + (20u<<20));        // 20..20.25MB L partials [2][8][4096]

  hipMemsetAsync(A, 0, (2u<<20), stream);
  edges_kernel<<<NE/256, 256, 0, stream>>>(ei, A);
  reach2_kernel<<<NN, 256, 0, stream>>>(A, M);
  conv_kernel<<<113, 256, 0, stream>>>(Wq,bq, Wk,bk, Wv,bv, x, Wtb, bb, xb);
  gemm_kernel<<<768, 256, 0, stream>>>(xb, Wtb, bb, QKV);
  vtrans_kernel<<<64, 256, 0, stream>>>(QKV, Vth);
  fattn_kernel<<<1024, 256, 0, stream>>>(M, QKV, Vth, attP, Lp);
  outln_kernel<<<512, 256, 0, stream>>>(attP, Lp, Wo, bo, x, lnw, lnb, (float*)d_out);
}

// Round 6
// 179.746 us; speedup vs baseline: 12.1389x; 1.0604x over previous
//
#include <hip/hip_runtime.h>
#include <math.h>

#define NN   4096
#define DM   256
#define NH   8
#define HDIM 32
#define NE   65536
#define ROWW 64
#define QS   0.25503473f   // log2(e)/sqrt(32)

typedef unsigned short u16t;
typedef unsigned int   u32t;
typedef unsigned long long u64t;
typedef __attribute__((ext_vector_type(8))) short bf16x8;
typedef __attribute__((ext_vector_type(4))) float f32x4;

__device__ __forceinline__ u16t f2bf(float f){            // RNE
  u32t x; __builtin_memcpy(&x,&f,4);
  u32t r=(x+0x7fffu+((x>>16)&1u))>>16;
  return (u16t)r;
}
__device__ __forceinline__ u16t f2bf_fast(float f){       // round-half-up (v>=0)
  u32t x; __builtin_memcpy(&x,&f,4);
  return (u16t)((x+0x8000u)>>16);
}
__device__ __forceinline__ float fexp2(float x){
#if __has_builtin(__builtin_amdgcn_exp2f)
  return __builtin_amdgcn_exp2f(x);
#else
  return exp2f(x);
#endif
}
__device__ __forceinline__ int sbfe1(u32t v, int pos){    // 0 or -1 from bit
#if __has_builtin(__builtin_amdgcn_sbfe)
  return __builtin_amdgcn_sbfe((int)v, pos, 1);
#else
  return ((int)(v << (31-pos))) >> 31;
#endif
}
__device__ __forceinline__ void gl2lds16(const void* g, void* l){
  auto gp = (const __attribute__((address_space(1))) u32t*)(unsigned long long)g;
  auto lp = (__attribute__((address_space(3))) u32t*)(u32t)(unsigned long long)l;
  __builtin_amdgcn_global_load_lds(gp, lp, 16, 0, 0);
}

// ---------------- mask build ----------------
__global__ __launch_bounds__(256) void edges_kernel(const int* __restrict__ ei, u64t* __restrict__ A){
  int e = blockIdx.x*256 + threadIdx.x;
  if (e < NE){
    int s = ei[e];
    int d = ei[NE + e];
    atomicOr(&A[(size_t)s*ROWW + (d>>6)], 1ull<<(d&63));
    atomicOr(&A[(size_t)d*ROWW + (s>>6)], 1ull<<(s&63));
  }
  if (e < NN){
    atomicOr(&A[(size_t)e*ROWW + (e>>6)], 1ull<<(e&63));
  }
}

__global__ __launch_bounds__(256) void reach2_kernel(const u64t* __restrict__ A, u64t* __restrict__ M){
  __shared__ u16t list[NN];
  __shared__ int  cnt;
  __shared__ u64t accs[256];
  const int tid = threadIdx.x;
  const int n   = blockIdx.x;
  const int t = tid & 63;
  const int g = tid >> 6;
  if (tid==0) cnt=0;
  __syncthreads();
  if (tid < ROWW){
    u64t w = A[(size_t)n*ROWW + tid];
    int base = tid*64;
    while (w){
      int b = __builtin_ctzll(w);
      w &= w-1;
      int i = atomicAdd(&cnt,1);
      list[i] = (u16t)(base+b);
    }
  }
  __syncthreads();
  const int c = cnt;
  u64t acc = 0;
  int i = g;
  // 4 independent loads in flight per iteration (break the waitcnt serialization)
  for (; i+12 < c; i += 16){
    u64t a0 = A[(size_t)list[i   ]*ROWW + t];
    u64t a1 = A[(size_t)list[i+4 ]*ROWW + t];
    u64t a2 = A[(size_t)list[i+8 ]*ROWW + t];
    u64t a3 = A[(size_t)list[i+12]*ROWW + t];
    acc |= a0 | a1 | a2 | a3;
  }
  for (; i < c; i += 4){
    acc |= A[(size_t)list[i]*ROWW + t];
  }
  accs[tid] = acc;
  __syncthreads();
  if (tid < ROWW){
    u64t a = accs[tid] | accs[64+tid] | accs[128+tid] | accs[192+tid];
    M[(size_t)n*ROWW + tid] = a;
  }
}

// ---------------- conversions: 4 W transposes->bf16 (Q scaled), bias fuse, x->bf16 ----------------
// grid 129: b 0..63 = W tiles (4 mats x 16), b 64 = bias, b 65..128 = x convert
__global__ __launch_bounds__(256) void conv_kernel(
    const float* __restrict__ Wq, const float* __restrict__ bq,
    const float* __restrict__ Wk, const float* __restrict__ bk,
    const float* __restrict__ Wv, const float* __restrict__ bv,
    const float* __restrict__ Wo, const float* __restrict__ x,
    u16t* __restrict__ Wtb, float* __restrict__ bb, u16t* __restrict__ xb)
{
  const int b = blockIdx.x, tid = threadIdx.x;
  if (b < 64){
    __shared__ __align__(16) float Tf[64*64];
    const int mat = b>>4, t = b&15;
    const int k0 = (t>>2)*64, nc0 = (t&3)*64;
    const float* W = mat==0? Wq : (mat==1? Wk : (mat==2? Wv : Wo));
    const float scale = (mat==0) ? QS : 1.0f;
    #pragma unroll
    for (int i=0;i<4;i++){
      int c = i*256+tid;
      int kk = c>>4, ch = c&15;
      float4 v = *(const float4*)(W + (size_t)(k0+kk)*256 + nc0 + ch*4);
      *(float4*)&Tf[kk*64 + ch*4] = v;
    }
    __syncthreads();
    const int nn = tid>>2, kc = tid&3;
    u32t pk[8];
    #pragma unroll
    for (int p=0;p<8;p++){
      float a  = Tf[(kc*16+2*p  )*64 + nn]*scale;
      float b2 = Tf[(kc*16+2*p+1)*64 + nn]*scale;
      pk[p] = (u32t)f2bf(a) | ((u32t)f2bf(b2)<<16);
    }
    u16t* o = Wtb + ((size_t)mat*256 + nc0 + nn)*256 + k0 + kc*16;
    *(uint4*)o     = make_uint4(pk[0],pk[1],pk[2],pk[3]);
    *(uint4*)(o+8) = make_uint4(pk[4],pk[5],pk[6],pk[7]);
  } else if (b == 64){
    #pragma unroll
    for (int i=0;i<3;i++){
      int j = i*256 + tid;
      bb[j] = (j<256) ? bq[j]*QS : ((j<512) ? bk[j-256] : bv[j-512]);
    }
  } else {
    const int bi = b-65;
    #pragma unroll
    for (int i=0;i<16;i++){
      int idx = (bi*256+tid) + i*16384;   // float4 chunks, 262144 total
      float4 v = *(const float4*)(x + (size_t)idx*4);
      u32t p0 = (u32t)f2bf(v.x) | ((u32t)f2bf(v.y)<<16);
      u32t p1 = (u32t)f2bf(v.z) | ((u32t)f2bf(v.w)<<16);
      *(uint2*)(xb + (size_t)idx*4) = make_uint2(p0,p1);
    }
  }
}

// ---------------- fused QKV GEMM: QKV[4096][768] = xb @ Wtb^T + bb ----------------
__global__ __launch_bounds__(256) void gemm_kernel(
    const u16t* __restrict__ xb, const u16t* __restrict__ Wtb,
    const float* __restrict__ bb, u16t* __restrict__ QKV)
{
  __shared__ __align__(16) u16t Xs[64*256];
  const int tid = threadIdx.x;
  const int w = tid>>6, lane = tid&63, l15 = lane&15, quad = lane>>4;
  const int mt = blockIdx.x / 12;
  const int nt = blockIdx.x % 12;
  const int m0 = mt*64, n0 = nt*64;
  #pragma unroll
  for (int i=0;i<8;i++){
    int c = i*256 + tid;
    int row = c>>5, pc = c&31;
    int lc = pc ^ (row&7);
    gl2lds16(xb + (size_t)(m0+row)*256 + lc*8, &Xs[(size_t)(i*256 + w*64)*8]);
  }
  __syncthreads();
  bf16x8 afr[8];
  {
    const int row = w*16 + l15;
    #pragma unroll
    for (int kc=0;kc<8;kc++){
      const int phys = (kc*4+quad) ^ (row&7);
      uint4 t = *(const uint4*)&Xs[row*256 + phys*8];
      __builtin_memcpy(&afr[kc], &t, 16);
    }
  }
  f32x4 acc[4];
  #pragma unroll
  for (int nf=0;nf<4;nf++){
    float b2 = bb[n0 + nf*16 + l15];
    acc[nf] = (f32x4){b2,b2,b2,b2};
  }
  #pragma unroll
  for (int nf=0;nf<4;nf++){
    const u16t* Bp = Wtb + (size_t)(n0 + nf*16 + l15)*256 + quad*8;
    #pragma unroll
    for (int kc=0;kc<8;kc++){
      uint4 t = *(const uint4*)(Bp + kc*32);
      bf16x8 bfr; __builtin_memcpy(&bfr,&t,16);
      acc[nf] = __builtin_amdgcn_mfma_f32_16x16x32_bf16(afr[kc], bfr, acc[nf], 0,0,0);
    }
  }
  #pragma unroll
  for (int nf=0;nf<4;nf++){
    const int col = n0 + nf*16 + l15;
    #pragma unroll
    for (int r=0;r<4;r++){
      const int m = m0 + w*16 + quad*4 + r;
      QKV[(size_t)m*768 + col] = f2bf(acc[nf][r]);
    }
  }
}

// ---------------- V transpose: QKV cols 512..767 -> Vth[256][4096] ----------------
__global__ __launch_bounds__(256) void vtrans_kernel(const u16t* __restrict__ QKV, u16t* __restrict__ Vth){
  __shared__ u16t Ts[64*256];
  const int tid = threadIdx.x;
  const int n0 = blockIdx.x*64;
  #pragma unroll
  for (int i=0;i<8;i++){
    int c = i*256+tid;
    int n = c>>5, ch = c&31;
    uint4 v = *(const uint4*)(QKV + (size_t)(n0+n)*768 + 512 + ch*8);
    *(uint4*)&Ts[n*256 + ch*8] = v;
  }
  __syncthreads();
  u32t pk[32];
  #pragma unroll
  for (int p=0;p<32;p++){
    u16t a = Ts[(2*p  )*256 + tid];
    u16t b = Ts[(2*p+1)*256 + tid];
    pk[p] = (u32t)a | ((u32t)b<<16);
  }
  u16t* o = Vth + (size_t)tid*NN + n0;
  #pragma unroll
  for (int q=0;q<8;q++)
    *(uint4*)(o + q*8) = make_uint4(pk[q*4],pk[q*4+1],pk[q*4+2],pk[q*4+3]);
}

// ---------------- dense flash attention (MFMA, no-max softmax, key-split x2) ----------------
__global__ __launch_bounds__(256) void fattn_kernel(
    const u64t* __restrict__ M, const u16t* __restrict__ QKV,
    const u16t* __restrict__ Vth,
    float* __restrict__ attP, float* __restrict__ Lp)
{
  __shared__ __align__(16) u16t Ks[2][64*HDIM];
  __shared__ __align__(16) u16t Vs[2][HDIM*64];
  __shared__ __align__(16) u64t Ms[2][64];
  __shared__ __align__(16) u16t Ps[4][16*64];

  const int tid  = threadIdx.x;
  const int w    = tid >> 6;
  const int lane = tid & 63;
  const int l15  = lane & 15;
  const int quad = lane >> 4;
  const int h    = blockIdx.x & 7;
  const int n0   = ((blockIdx.x >> 3) & 63) * 64;
  const int half = blockIdx.x >> 9;
  const int k0   = half * 32;

  const u16t* Kg = QKV + 256 + h*HDIM;          // row-major stride 768
  const u16t* Vg = Vth + (size_t)h*HDIM*NN;
  const int kr = tid>>2, kqp = tid&3;
  const int kgo = kr*768 + (kqp ^ ((kr>>1)&3))*8;
  const int vr = tid>>3, vqp = tid&7;
  const int vgo = vr*NN + (vqp ^ (vr&7))*8;

  bf16x8 qfrag;
  {
    const u16t* qp = QKV + (size_t)(n0 + w*16 + l15)*768 + h*HDIM + quad*8;
    uint4 t = *(const uint4*)qp;
    __builtin_memcpy(&qfrag, &t, 16);
  }

  float lrow[4] = {0.f,0.f,0.f,0.f};
  f32x4 Oacc[2] = {{0.f,0.f,0.f,0.f},{0.f,0.f,0.f,0.f}};
  const f32x4 zero = {0.f,0.f,0.f,0.f};

  #define STAGE(kt, buf) do { \
    gl2lds16(Kg + (size_t)(kt)*64*768 + kgo, &Ks[(buf)][w*512]); \
    gl2lds16(Vg + (size_t)(kt)*64 + vgo,  &Vs[(buf)][w*512]); \
    if (tid < 64) Ms[(buf)][tid] = M[(size_t)(n0+tid)*ROWW + (kt)]; \
  } while(0)

  STAGE(k0, 0);
  const int kswz = (l15>>1)&3;
  const int pswz = l15&7;

  for (int ti=0; ti<32; ++ti){
    __syncthreads();
    if (ti < 31) STAGE(k0+ti+1, (ti+1)&1);
    const int buf = ti&1;

    f32x4 S[4];
    #pragma unroll
    for (int g=0; g<4; ++g){
      const u16t* kp = &Ks[buf][(g*16+l15)*HDIM + (quad ^ kswz)*8];
      uint4 t = *(const uint4*)kp;
      bf16x8 kb; __builtin_memcpy(&kb,&t,16);
      S[g] = __builtin_amdgcn_mfma_f32_16x16x32_bf16(qfrag, kb, zero, 0,0,0);
    }

    // p = exp2(S) AND sign-extended mask bit (2 VALU ops/elem for masking)
    u32t slo[4], shi[4];
    #pragma unroll
    for (int r=0;r<4;r++){
      u64t sh = Ms[buf][quad*4+r] >> l15;
      slo[r] = (u32t)sh; shi[r] = (u32t)(sh>>32);
    }
    #pragma unroll
    for (int g=0; g<4; ++g){
      #pragma unroll
      for (int r=0;r<4;r++){
        float p = fexp2(S[g][r]);
        int bm = sbfe1(g<2 ? slo[r] : shi[r], (g&1)*16);
        u32t pi; __builtin_memcpy(&pi,&p,4);
        pi &= (u32t)bm;
        __builtin_memcpy(&p,&pi,4);
        S[g][r] = p;
        lrow[r] += p;
      }
    }

    #pragma unroll
    for (int g=0; g<4; ++g){
      const int ch = g*2 + (l15>>3);
      #pragma unroll
      for (int r=0;r<4;r++){
        const int pr = quad*4+r;
        Ps[w][pr*64 + (ch ^ (pr&7))*8 + (l15&7)] = f2bf_fast(S[g][r]);
      }
    }

    #pragma unroll
    for (int kc=0; kc<2; ++kc){
      const u16t* pp = &Ps[w][l15*64 + ((kc*4+quad) ^ pswz)*8];
      uint4 ta = *(const uint4*)pp;
      bf16x8 pa; __builtin_memcpy(&pa,&ta,16);
      #pragma unroll
      for (int dh=0; dh<2; ++dh){
        const u16t* vp = &Vs[buf][(dh*16+l15)*64 + ((kc*4+quad) ^ pswz)*8];
        uint4 tb = *(const uint4*)vp;
        bf16x8 vb; __builtin_memcpy(&vb,&tb,16);
        Oacc[dh] = __builtin_amdgcn_mfma_f32_16x16x32_bf16(pa, vb, Oacc[dh], 0,0,0);
      }
    }
  }
  #undef STAGE

  #pragma unroll
  for (int r=0;r<4;r++){
    float l = lrow[r];
    l += __shfl_xor(l,1); l += __shfl_xor(l,2); l += __shfl_xor(l,4); l += __shfl_xor(l,8);
    const int n = n0 + w*16 + quad*4 + r;
    if (l15 == 0) Lp[(size_t)half*NH*NN + (size_t)h*NN + n] = l;
    float* op = attP + ((size_t)half*NN + n)*DM + h*HDIM;
    op[l15]    = Oacc[0][r];
    op[16+l15] = Oacc[1][r];
  }
}

// ---------------- merge + out-proj (MFMA) + residual + layernorm ----------------
// grid 256: 16 rows/block. 4 waves x 64 cols each. Wo^T bf16 at Wtb mat=3.
__global__ __launch_bounds__(256) void outln_kernel(
    const float* __restrict__ attP, const float* __restrict__ Lp,
    const u16t* __restrict__ WoT, const float* __restrict__ bo,
    const float* __restrict__ x, const float* __restrict__ lnw, const float* __restrict__ lnb,
    float* __restrict__ out)
{
  __shared__ __align__(16) u16t As[16*256];   // merged, normalized att (bf16, swizzled)
  __shared__ float Lr[8*16];                  // 1/l per (head,row)
  __shared__ float red1[16][4], red2[16][4];
  const int tid = threadIdx.x;
  const int w = tid>>6, lane = tid&63, l15 = lane&15, quad = lane>>4;
  const int n0 = blockIdx.x*16;

  if (tid < 128){
    int hh = tid>>4, rr = tid&15;
    float l = Lp[(size_t)hh*NN + n0+rr] + Lp[(size_t)NH*NN + (size_t)hh*NN + n0+rr];
    Lr[tid] = 1.f/l;
  }
  __syncthreads();
  // merge halves -> normalized bf16 A-tile in LDS (swizzled 8-elem chunks)
  #pragma unroll
  for (int it=0; it<4; ++it){
    int e = it*256 + tid;           // 1024 float4-chunks = 16 rows x 64
    int n = e>>6, c4 = e&63;
    float4 a0 = ((const float4*)(attP + (size_t)(n0+n)*DM))[c4];
    float4 a1 = ((const float4*)(attP + (size_t)(NN+n0+n)*DM))[c4];
    float rinv = Lr[(c4>>3)*16 + n];
    float v0=(a0.x+a1.x)*rinv, v1=(a0.y+a1.y)*rinv, v2=(a0.z+a1.z)*rinv, v3=(a0.w+a1.w)*rinv;
    u32t p0 = (u32t)f2bf(v0) | ((u32t)f2bf(v1)<<16);
    u32t p1 = (u32t)f2bf(v2) | ((u32t)f2bf(v3)<<16);
    *(uint2*)&As[n*256 + ((c4>>1)^(n&7))*8 + (c4&1)*4] = make_uint2(p0,p1);
  }
  __syncthreads();

  bf16x8 afr[8];
  #pragma unroll
  for (int kc=0;kc<8;kc++){
    const int phys = (kc*4+quad) ^ (l15&7);
    uint4 t = *(const uint4*)&As[l15*256 + phys*8];
    __builtin_memcpy(&afr[kc], &t, 16);
  }
  f32x4 acc[4];
  #pragma unroll
  for (int nf=0;nf<4;nf++){
    const int col = w*64 + nf*16 + l15;
    float b2 = bo[col];
    acc[nf] = (f32x4){b2,b2,b2,b2};
    const u16t* Bp = WoT + (size_t)col*256 + quad*8;
    #pragma unroll
    for (int kc=0;kc<8;kc++){
      uint4 t = *(const uint4*)(Bp + kc*32);
      bf16x8 bfr; __builtin_memcpy(&bfr,&t,16);
      acc[nf] = __builtin_amdgcn_mfma_f32_16x16x32_bf16(afr[kc], bfr, acc[nf], 0,0,0);
    }
  }
  // residual + LN partials (rows quad*4+r, cols w*64+nf*16+l15)
  float ps1[4]={0,0,0,0}, ps2[4]={0,0,0,0};
  #pragma unroll
  for (int nf=0;nf<4;nf++){
    const int col = w*64 + nf*16 + l15;
    #pragma unroll
    for (int r=0;r<4;r++){
      float v = acc[nf][r] + x[(size_t)(n0+quad*4+r)*DM + col];
      acc[nf][r] = v;
      ps1[r] += v;
      ps2[r] += v*v;
    }
  }
  #pragma unroll
  for (int r=0;r<4;r++){
    ps1[r] += __shfl_xor(ps1[r],1); ps2[r] += __shfl_xor(ps2[r],1);
    ps1[r] += __shfl_xor(ps1[r],2); ps2[r] += __shfl_xor(ps2[r],2);
    ps1[r] += __shfl_xor(ps1[r],4); ps2[r] += __shfl_xor(ps2[r],4);
    ps1[r] += __shfl_xor(ps1[r],8); ps2[r] += __shfl_xor(ps2[r],8);
    if (l15==0){ red1[quad*4+r][w]=ps1[r]; red2[quad*4+r][w]=ps2[r]; }
  }
  __syncthreads();
  float mu[4], rs[4];
  #pragma unroll
  for (int r=0;r<4;r++){
    const int row = quad*4+r;
    float s1 = red1[row][0]+red1[row][1]+red1[row][2]+red1[row][3];
    float s2 = red2[row][0]+red2[row][1]+red2[row][2]+red2[row][3];
    mu[r] = s1*(1.0f/256.0f);
    float var = s2*(1.0f/256.0f) - mu[r]*mu[r];
    rs[r] = rsqrtf(var+1e-5f);
  }
  #pragma unroll
  for (int nf=0;nf<4;nf++){
    const int col = w*64 + nf*16 + l15;
    const float lw = lnw[col], lb = lnb[col];
    #pragma unroll
    for (int r=0;r<4;r++){
      out[(size_t)(n0+quad*4+r)*DM + col] = (acc[nf][r]-mu[r])*rs[r]*lw + lb;
    }
  }
}

extern "C" void kernel_launch(void* const* d_in, const int* in_sizes, int n_in,
                              void* d_out, int out_size, void* d_ws, size_t ws_size,
                              hipStream_t stream) {
  const float* x   = (const float*)d_in[0];
  const int*   ei  = (const int*  )d_in[1];
  const float* Wq  = (const float*)d_in[2];
  const float* bq  = (const float*)d_in[3];
  const float* Wk  = (const float*)d_in[4];
  const float* bk  = (const float*)d_in[5];
  const float* Wv  = (const float*)d_in[6];
  const float* bv  = (const float*)d_in[7];
  const float* Wo  = (const float*)d_in[8];
  const float* bo  = (const float*)d_in[9];
  const float* lnw = (const float*)d_in[10];
  const float* lnb = (const float*)d_in[11];

  char* ws = (char*)d_ws;
  u64t*  A    = (u64t*)(ws);                     // 0..2MB adjacency bits
  u64t*  M    = (u64t*)(ws + (2u<<20));          // 2..4MB reach-2 bits
  u16t*  xb   = (u16t*)(ws + (4u<<20));          // 4..6MB x bf16 (dead after gemm)
  float* attP = (float*)(ws + (4u<<20));         // 4..12MB O partials (after gemm)
  u16t*  QKV  = (u16t*)(ws + (12u<<20));         // 12..18MB fused QKV bf16 [4096][768]
  u16t*  Vth  = (u16t*)(ws + (18u<<20));         // 18..20MB V^T bf16 [256][4096]
  float* Lp   = (float*)(ws + (20u<<20));        // 20..20.25MB L partials [2][8][4096]
  u16t*  Wtb  = (u16t*)(ws + (20736u<<10));      // 20.25..20.75MB W^T bf16 (4 mats, persists)
  float* bb   = (float*)(ws + (21248u<<10));     // 20.75..20.76MB qkv bias fp32

  hipMemsetAsync(A, 0, (2u<<20), stream);
  edges_kernel<<<NE/256, 256, 0, stream>>>(ei, A);
  reach2_kernel<<<NN, 256, 0, stream>>>(A, M);
  conv_kernel<<<129, 256, 0, stream>>>(Wq,bq, Wk,bk, Wv,bv, Wo, x, Wtb, bb, xb);
  gemm_kernel<<<768, 256, 0, stream>>>(xb, Wtb, bb, QKV);
  vtrans_kernel<<<64, 256, 0, stream>>>(QKV, Vth);
  fattn_kernel<<<1024, 256, 0, stream>>>(M, QKV, Vth, attP, Lp);
  outln_kernel<<<256, 256, 0, stream>>>(attP, Lp, Wtb + (size_t)3*256*256, bo, x, lnw, lnb, (float*)d_out);
}

// Round 7
// 166.033 us; speedup vs baseline: 13.1414x; 1.0826x over previous
//
#include <hip/hip_runtime.h>
#include <math.h>

#define NN   4096
#define DM   256
#define NH   8
#define HDIM 32
#define NE   65536
#define ROWW 64
#define QS   0.25503473f   // log2(e)/sqrt(32)

typedef unsigned short u16t;
typedef unsigned int   u32t;
typedef unsigned long long u64t;
typedef __attribute__((ext_vector_type(8))) short bf16x8;
typedef __attribute__((ext_vector_type(4))) float f32x4;

__device__ __forceinline__ u16t f2bf(float f){            // RNE
  u32t x; __builtin_memcpy(&x,&f,4);
  u32t r=(x+0x7fffu+((x>>16)&1u))>>16;
  return (u16t)r;
}
__device__ __forceinline__ float fexp2(float x){
#if __has_builtin(__builtin_amdgcn_exp2f)
  return __builtin_amdgcn_exp2f(x);
#else
  return exp2f(x);
#endif
}
__device__ __forceinline__ int sbfe1(u32t v, int pos){    // 0 or -1 from bit
#if __has_builtin(__builtin_amdgcn_sbfe)
  return __builtin_amdgcn_sbfe((int)v, pos, 1);
#else
  return ((int)(v << (31-pos))) >> 31;
#endif
}
// pack hi16 of (a+0x8000) and (b+0x8000) -> u32 (lo16 from a)
__device__ __forceinline__ u32t pk2(float a, float b){
  u32t xa, xb;
  __builtin_memcpy(&xa,&a,4); __builtin_memcpy(&xb,&b,4);
  xa += 0x8000u; xb += 0x8000u;
#if __has_builtin(__builtin_amdgcn_perm)
  return __builtin_amdgcn_perm(xb, xa, 0x07060302u);
#else
  return (xa>>16) | (xb & 0xffff0000u);
#endif
}
__device__ __forceinline__ void gl2lds16(const void* g, void* l){
  auto gp = (const __attribute__((address_space(1))) u32t*)(unsigned long long)g;
  auto lp = (__attribute__((address_space(3))) u32t*)(u32t)(unsigned long long)l;
  __builtin_amdgcn_global_load_lds(gp, lp, 16, 0, 0);
}

// ---------------- K0: zero A + W transposes + bias + x->bf16 ----------------
// grid 193: b 0..63 zero A; 64..127 W tiles (4 mats x 16); 128 bias; 129..192 x
__global__ __launch_bounds__(256) void conv_kernel(
    const float* __restrict__ Wq, const float* __restrict__ bq,
    const float* __restrict__ Wk, const float* __restrict__ bk,
    const float* __restrict__ Wv, const float* __restrict__ bv,
    const float* __restrict__ Wo, const float* __restrict__ x,
    u16t* __restrict__ Wtb, float* __restrict__ bb, u16t* __restrict__ xb,
    uint4* __restrict__ A4)
{
  const int b = blockIdx.x, tid = threadIdx.x;
  if (b < 64){
    const uint4 z = make_uint4(0,0,0,0);
    #pragma unroll
    for (int i=0;i<8;i++) A4[(size_t)b*2048 + i*256 + tid] = z;
  } else if (b < 128){
    __shared__ __align__(16) float Tf[64*64];
    const int mat = (b-64)>>4, t = b&15;
    const int k0 = (t>>2)*64, nc0 = (t&3)*64;
    const float* W = mat==0? Wq : (mat==1? Wk : (mat==2? Wv : Wo));
    const float scale = (mat==0) ? QS : 1.0f;
    #pragma unroll
    for (int i=0;i<4;i++){
      int c = i*256+tid;
      int kk = c>>4, ch = c&15;
      float4 v = *(const float4*)(W + (size_t)(k0+kk)*256 + nc0 + ch*4);
      *(float4*)&Tf[kk*64 + ch*4] = v;
    }
    __syncthreads();
    const int nn = tid>>2, kc = tid&3;
    u32t pk[8];
    #pragma unroll
    for (int p=0;p<8;p++){
      float a  = Tf[(kc*16+2*p  )*64 + nn]*scale;
      float b2 = Tf[(kc*16+2*p+1)*64 + nn]*scale;
      pk[p] = (u32t)f2bf(a) | ((u32t)f2bf(b2)<<16);
    }
    u16t* o = Wtb + ((size_t)mat*256 + nc0 + nn)*256 + k0 + kc*16;
    *(uint4*)o     = make_uint4(pk[0],pk[1],pk[2],pk[3]);
    *(uint4*)(o+8) = make_uint4(pk[4],pk[5],pk[6],pk[7]);
  } else if (b == 128){
    #pragma unroll
    for (int i=0;i<3;i++){
      int j = i*256 + tid;
      bb[j] = (j<256) ? bq[j]*QS : ((j<512) ? bk[j-256] : bv[j-512]);
    }
  } else {
    const int bi = b-129;
    #pragma unroll
    for (int i=0;i<16;i++){
      int idx = (bi*256+tid) + i*16384;   // float4 chunks, 262144 total
      float4 v = *(const float4*)(x + (size_t)idx*4);
      u32t p0 = (u32t)f2bf(v.x) | ((u32t)f2bf(v.y)<<16);
      u32t p1 = (u32t)f2bf(v.z) | ((u32t)f2bf(v.w)<<16);
      *(uint2*)(xb + (size_t)idx*4) = make_uint2(p0,p1);
    }
  }
}

// ---------------- K1: QKV GEMM (+direct V^T store) + edge bitmask ----------------
// grid 1024: b 0..767 gemm (mt=b/12, nt=b%12; nt>=8 => V, transposed store);
//            b 768..1023 edges.
__global__ __launch_bounds__(256) void work1_kernel(
    const u16t* __restrict__ xb, const u16t* __restrict__ Wtb,
    const float* __restrict__ bb, u16t* __restrict__ QKV, u16t* __restrict__ Vth,
    const int* __restrict__ ei, u64t* __restrict__ A)
{
  const int bx = blockIdx.x, tid = threadIdx.x;
  if (bx >= 768){
    int e = (bx-768)*256 + tid;
    int s = ei[e];
    int d = ei[NE + e];
    atomicOr(&A[(size_t)s*ROWW + (d>>6)], 1ull<<(d&63));
    atomicOr(&A[(size_t)d*ROWW + (s>>6)], 1ull<<(s&63));
    if (e < NN) atomicOr(&A[(size_t)e*ROWW + (e>>6)], 1ull<<(e&63));
    return;
  }
  __shared__ __align__(16) u16t Xs[64*256];
  const int w = tid>>6, lane = tid&63, l15 = lane&15, quad = lane>>4;
  const int mt = bx / 12;
  const int nt = bx % 12;
  const int m0 = mt*64, n0 = nt*64;
  #pragma unroll
  for (int i=0;i<8;i++){
    int c = i*256 + tid;
    int row = c>>5, pc = c&31;
    int lc = pc ^ (row&7);
    gl2lds16(xb + (size_t)(m0+row)*256 + lc*8, &Xs[(size_t)(i*256 + w*64)*8]);
  }
  __syncthreads();
  bf16x8 afr[8];
  {
    const int row = w*16 + l15;
    #pragma unroll
    for (int kc=0;kc<8;kc++){
      const int phys = (kc*4+quad) ^ (row&7);
      uint4 t = *(const uint4*)&Xs[row*256 + phys*8];
      __builtin_memcpy(&afr[kc], &t, 16);
    }
  }
  f32x4 acc[4];
  #pragma unroll
  for (int nf=0;nf<4;nf++){
    float b2 = bb[n0 + nf*16 + l15];
    acc[nf] = (f32x4){b2,b2,b2,b2};
  }
  #pragma unroll
  for (int nf=0;nf<4;nf++){
    const u16t* Bp = Wtb + (size_t)(n0 + nf*16 + l15)*256 + quad*8;
    #pragma unroll
    for (int kc=0;kc<8;kc++){
      uint4 t = *(const uint4*)(Bp + kc*32);
      bf16x8 bfr; __builtin_memcpy(&bfr,&t,16);
      acc[nf] = __builtin_amdgcn_mfma_f32_16x16x32_bf16(afr[kc], bfr, acc[nf], 0,0,0);
    }
  }
  if (nt < 8){
    #pragma unroll
    for (int nf=0;nf<4;nf++){
      const int col = n0 + nf*16 + l15;
      #pragma unroll
      for (int r=0;r<4;r++){
        const int m = m0 + w*16 + quad*4 + r;
        QKV[(size_t)m*512 + col] = f2bf(acc[nf][r]);
      }
    }
  } else {
    #pragma unroll
    for (int nf=0;nf<4;nf++){
      const int vcol = n0 - 512 + nf*16 + l15;   // 0..255 = h*32+d
      #pragma unroll
      for (int r=0;r<4;r++){
        const int m = m0 + w*16 + quad*4 + r;
        Vth[(size_t)vcol*NN + m] = f2bf(acc[nf][r]);
      }
    }
  }
}

// ---------------- K2: reach-2 mask ----------------
__global__ __launch_bounds__(256) void reach2_kernel(const u64t* __restrict__ A, u64t* __restrict__ M){
  __shared__ u16t list[NN];
  __shared__ int  cnt;
  __shared__ u64t accs[256];
  const int tid = threadIdx.x;
  const int n   = blockIdx.x;
  const int t = tid & 63;
  const int g = tid >> 6;
  if (tid==0) cnt=0;
  __syncthreads();
  if (tid < ROWW){
    u64t w = A[(size_t)n*ROWW + tid];
    int base = tid*64;
    while (w){
      int b = __builtin_ctzll(w);
      w &= w-1;
      int i = atomicAdd(&cnt,1);
      list[i] = (u16t)(base+b);
    }
  }
  __syncthreads();
  const int c = cnt;
  u64t acc = 0;
  int i = g;
  for (; i+12 < c; i += 16){
    u64t a0 = A[(size_t)list[i   ]*ROWW + t];
    u64t a1 = A[(size_t)list[i+4 ]*ROWW + t];
    u64t a2 = A[(size_t)list[i+8 ]*ROWW + t];
    u64t a3 = A[(size_t)list[i+12]*ROWW + t];
    acc |= a0 | a1 | a2 | a3;
  }
  for (; i < c; i += 4){
    acc |= A[(size_t)list[i]*ROWW + t];
  }
  accs[tid] = acc;
  __syncthreads();
  if (tid < ROWW){
    u64t a = accs[tid] | accs[64+tid] | accs[128+tid] | accs[192+tid];
    M[(size_t)n*ROWW + tid] = a;
  }
}

// ---------------- K3: flash attention, S^T scheme, key-split x3 ----------------
// grid 1536: h = bx&7, qt = (bx>>3)&63, third = bx>>9 (0..2).
__global__ __launch_bounds__(256) void fattn_kernel(
    const u64t* __restrict__ M, const u16t* __restrict__ QKV,
    const u16t* __restrict__ Vth,
    float* __restrict__ attP, float* __restrict__ Lp)
{
  __shared__ __align__(16) u16t Ks[2][64*HDIM];
  __shared__ __align__(16) u16t Vs[2][HDIM*64];
  __shared__ __align__(16) u64t Ms[2][64];
  __shared__ __align__(16) u16t Ps[4][16*64];

  const int tid  = threadIdx.x;
  const int w    = tid >> 6;
  const int lane = tid & 63;
  const int l15  = lane & 15;
  const int quad = lane >> 4;
  const int h    = blockIdx.x & 7;
  const int n0   = ((blockIdx.x >> 3) & 63) * 64;
  const int third= blockIdx.x >> 9;
  const int kb   = (third*64)/3;        // 0,21,42
  const int ke   = ((third+1)*64)/3;    // 21,42,64

  const u16t* Kg = QKV + 256 + h*HDIM;          // row-major stride 512
  const u16t* Vg = Vth + (size_t)h*HDIM*NN;
  const int kr = tid>>2, kqp = tid&3;
  const int kgo = kr*512 + (kqp ^ ((kr>>1)&3))*8;
  const int vr = tid>>3, vqp = tid&7;
  const int vgo = vr*NN + (vqp ^ (vr&7))*8;

  bf16x8 qfrag;   // B-operand now; layout identical to old A-usage
  {
    const u16t* qp = QKV + (size_t)(n0 + w*16 + l15)*512 + h*HDIM + quad*8;
    uint4 t = *(const uint4*)qp;
    __builtin_memcpy(&qfrag, &t, 16);
  }

  float lsum = 0.f;                     // q-row w*16+l15, this quad's keys
  f32x4 Oacc[2] = {{0.f,0.f,0.f,0.f},{0.f,0.f,0.f,0.f}};
  const f32x4 zero = {0.f,0.f,0.f,0.f};

  #define STAGE(kt, buf) do { \
    gl2lds16(Kg + (size_t)(kt)*64*512 + kgo, &Ks[(buf)][w*512]); \
    gl2lds16(Vg + (size_t)(kt)*64 + vgo,  &Vs[(buf)][w*512]); \
    if (tid < 64) Ms[(buf)][tid] = M[(size_t)(n0+tid)*ROWW + (kt)]; \
  } while(0)

  STAGE(kb, kb&1);
  const int kswz = (l15>>1)&3;
  const int pswz = l15&7;
  const int e2   = (l15&7)<<1;          // 4-u16-chunk swizzle for Ps

  for (int kt=kb; kt<ke; ++kt){
    __syncthreads();
    if (kt+1 < ke) STAGE(kt+1, (kt+1)&1);
    const int buf = kt&1;

    // S^T = K Q^T : lane holds rows = keys g*16+quad*4+(0..3), col = q-row l15
    f32x4 S[4];
    #pragma unroll
    for (int g=0; g<4; ++g){
      const u16t* kp = &Ks[buf][(g*16+l15)*HDIM + (quad ^ kswz)*8];
      uint4 t = *(const uint4*)kp;
      bf16x8 kb8; __builtin_memcpy(&kb8,&t,16);
      S[g] = __builtin_amdgcn_mfma_f32_16x16x32_bf16(kb8, qfrag, zero, 0,0,0);
    }

    // mask word for this lane's q-row (broadcast across quads)
    u64t mw = Ms[buf][w*16+l15] >> (quad*4);
    u32t slo = (u32t)mw, shi = (u32t)(mw>>32);
    #pragma unroll
    for (int g=0; g<4; ++g){
      const u32t sv = (g<2)? slo : shi;
      const int base = (g&1)*16;
      #pragma unroll
      for (int r=0;r<4;r++){
        float p = fexp2(S[g][r]);
        int bm = sbfe1(sv, base+r);
        u32t pi; __builtin_memcpy(&pi,&p,4);
        pi &= (u32t)bm;
        __builtin_memcpy(&p,&pi,4);
        S[g][r] = p;
        lsum += p;
      }
    }

    // P: pack 4 consecutive keys -> one b64 write per g
    #pragma unroll
    for (int g=0; g<4; ++g){
      u32t lo = pk2(S[g][0], S[g][1]);
      u32t hi = pk2(S[g][2], S[g][3]);
      *(uint2*)&Ps[w][l15*64 + (((g*4+quad) ^ e2)<<2)] = make_uint2(lo,hi);
    }

    // O += P V
    #pragma unroll
    for (int kc=0; kc<2; ++kc){
      const u16t* pp = &Ps[w][l15*64 + (((kc*8+quad*2) ^ e2)<<2)];
      uint4 ta = *(const uint4*)pp;
      bf16x8 pa; __builtin_memcpy(&pa,&ta,16);
      #pragma unroll
      for (int dh=0; dh<2; ++dh){
        const u16t* vp = &Vs[buf][(dh*16+l15)*64 + ((kc*4+quad) ^ pswz)*8];
        uint4 tb = *(const uint4*)vp;
        bf16x8 vb; __builtin_memcpy(&vb,&tb,16);
        Oacc[dh] = __builtin_amdgcn_mfma_f32_16x16x32_bf16(pa, vb, Oacc[dh], 0,0,0);
      }
    }
  }
  #undef STAGE

  // epilogue: L reduce across quads; store raw partials
  float l = lsum;
  l += __shfl_xor(l,16);
  l += __shfl_xor(l,32);
  if (quad==0) Lp[(size_t)third*NH*NN + (size_t)h*NN + n0 + w*16 + l15] = l;
  #pragma unroll
  for (int r=0;r<4;r++){
    const int n = n0 + w*16 + quad*4 + r;
    float* op = attP + ((size_t)third*NN + n)*DM + h*HDIM;
    op[l15]    = Oacc[0][r];
    op[16+l15] = Oacc[1][r];
  }
}

// ---------------- K4: merge + out-proj (MFMA) + residual + layernorm ----------------
__global__ __launch_bounds__(256) void outln_kernel(
    const float* __restrict__ attP, const float* __restrict__ Lp,
    const u16t* __restrict__ WoT, const float* __restrict__ bo,
    const float* __restrict__ x, const float* __restrict__ lnw, const float* __restrict__ lnb,
    float* __restrict__ out)
{
  __shared__ __align__(16) u16t As[16*256];
  __shared__ float Lr[8*16];
  __shared__ float red1[16][4], red2[16][4];
  const int tid = threadIdx.x;
  const int w = tid>>6, lane = tid&63, l15 = lane&15, quad = lane>>4;
  const int n0 = blockIdx.x*16;

  if (tid < 128){
    int hh = tid>>4, rr = tid&15;
    float l = Lp[(size_t)hh*NN + n0+rr]
            + Lp[(size_t)NH*NN + (size_t)hh*NN + n0+rr]
            + Lp[(size_t)2*NH*NN + (size_t)hh*NN + n0+rr];
    Lr[tid] = 1.f/l;
  }
  __syncthreads();
  #pragma unroll
  for (int it=0; it<4; ++it){
    int e = it*256 + tid;           // 1024 float4-chunks = 16 rows x 64
    int n = e>>6, c4 = e&63;
    float4 a0 = ((const float4*)(attP + (size_t)(n0+n)*DM))[c4];
    float4 a1 = ((const float4*)(attP + (size_t)(NN+n0+n)*DM))[c4];
    float4 a2 = ((const float4*)(attP + (size_t)(2*NN+n0+n)*DM))[c4];
    float rinv = Lr[(c4>>3)*16 + n];
    float v0=(a0.x+a1.x+a2.x)*rinv, v1=(a0.y+a1.y+a2.y)*rinv;
    float v2=(a0.z+a1.z+a2.z)*rinv, v3=(a0.w+a1.w+a2.w)*rinv;
    u32t p0 = (u32t)f2bf(v0) | ((u32t)f2bf(v1)<<16);
    u32t p1 = (u32t)f2bf(v2) | ((u32t)f2bf(v3)<<16);
    *(uint2*)&As[n*256 + ((c4>>1)^(n&7))*8 + (c4&1)*4] = make_uint2(p0,p1);
  }
  __syncthreads();

  bf16x8 afr[8];
  #pragma unroll
  for (int kc=0;kc<8;kc++){
    const int phys = (kc*4+quad) ^ (l15&7);
    uint4 t = *(const uint4*)&As[l15*256 + phys*8];
    __builtin_memcpy(&afr[kc], &t, 16);
  }
  f32x4 acc[4];
  #pragma unroll
  for (int nf=0;nf<4;nf++){
    const int col = w*64 + nf*16 + l15;
    float b2 = bo[col];
    acc[nf] = (f32x4){b2,b2,b2,b2};
    const u16t* Bp = WoT + (size_t)col*256 + quad*8;
    #pragma unroll
    for (int kc=0;kc<8;kc++){
      uint4 t = *(const uint4*)(Bp + kc*32);
      bf16x8 bfr; __builtin_memcpy(&bfr,&t,16);
      acc[nf] = __builtin_amdgcn_mfma_f32_16x16x32_bf16(afr[kc], bfr, acc[nf], 0,0,0);
    }
  }
  float ps1[4]={0,0,0,0}, ps2[4]={0,0,0,0};
  #pragma unroll
  for (int nf=0;nf<4;nf++){
    const int col = w*64 + nf*16 + l15;
    #pragma unroll
    for (int r=0;r<4;r++){
      float v = acc[nf][r] + x[(size_t)(n0+quad*4+r)*DM + col];
      acc[nf][r] = v;
      ps1[r] += v;
      ps2[r] += v*v;
    }
  }
  #pragma unroll
  for (int r=0;r<4;r++){
    ps1[r] += __shfl_xor(ps1[r],1); ps2[r] += __shfl_xor(ps2[r],1);
    ps1[r] += __shfl_xor(ps1[r],2); ps2[r] += __shfl_xor(ps2[r],2);
    ps1[r] += __shfl_xor(ps1[r],4); ps2[r] += __shfl_xor(ps2[r],4);
    ps1[r] += __shfl_xor(ps1[r],8); ps2[r] += __shfl_xor(ps2[r],8);
    if (l15==0){ red1[quad*4+r][w]=ps1[r]; red2[quad*4+r][w]=ps2[r]; }
  }
  __syncthreads();
  float mu[4], rs[4];
  #pragma unroll
  for (int r=0;r<4;r++){
    const int row = quad*4+r;
    float s1 = red1[row][0]+red1[row][1]+red1[row][2]+red1[row][3];
    float s2 = red2[row][0]+red2[row][1]+red2[row][2]+red2[row][3];
    mu[r] = s1*(1.0f/256.0f);
    float var = s2*(1.0f/256.0f) - mu[r]*mu[r];
    rs[r] = rsqrtf(var+1e-5f);
  }
  #pragma unroll
  for (int nf=0;nf<4;nf++){
    const int col = w*64 + nf*16 + l15;
    const float lw = lnw[col], lb = lnb[col];
    #pragma unroll
    for (int r=0;r<4;r++){
      out[(size_t)(n0+quad*4+r)*DM + col] = (acc[nf][r]-mu[r])*rs[r]*lw + lb;
    }
  }
}

extern "C" void kernel_launch(void* const* d_in, const int* in_sizes, int n_in,
                              void* d_out, int out_size, void* d_ws, size_t ws_size,
                              hipStream_t stream) {
  const float* x   = (const float*)d_in[0];
  const int*   ei  = (const int*  )d_in[1];
  const float* Wq  = (const float*)d_in[2];
  const float* bq  = (const float*)d_in[3];
  const float* Wk  = (const float*)d_in[4];
  const float* bk  = (const float*)d_in[5];
  const float* Wv  = (const float*)d_in[6];
  const float* bv  = (const float*)d_in[7];
  const float* Wo  = (const float*)d_in[8];
  const float* bo  = (const float*)d_in[9];
  const float* lnw = (const float*)d_in[10];
  const float* lnb = (const float*)d_in[11];

  char* ws = (char*)d_ws;
  u64t*  A    = (u64t*)(ws);                     // 0..2MB adjacency bits (zeroed in K0)
  u64t*  M    = (u64t*)(ws + (2u<<20));          // 2..4MB reach-2 bits
  float* attP = (float*)(ws + (4u<<20));         // 4..16MB O partials [3][4096][256] fp32
  u16t*  xb   = (u16t*)(ws + (4u<<20));          // alias attP[0]: conv->gemm only, dead before fattn
  u16t*  QKV  = (u16t*)(ws + (16u<<20));         // 16..20MB [4096][512] bf16 (Q|K)
  u16t*  Vth  = (u16t*)(ws + (20u<<20));         // 20..22MB [256][4096] bf16 V^T
  float* Lp   = (float*)(ws + (22u<<20));        // 22..22.4MB L partials [3][8][4096]
  u16t*  Wtb  = (u16t*)(ws + (23u<<20));         // 23..23.5MB W^T bf16 (4 mats)
  float* bb   = (float*)(ws + (23u<<20) + (512u<<10)); // bias fp32 (768)

  conv_kernel <<<193,  256, 0, stream>>>(Wq,bq, Wk,bk, Wv,bv, Wo, x, Wtb, bb, xb, (uint4*)A);
  work1_kernel<<<1024, 256, 0, stream>>>(xb, Wtb, bb, QKV, Vth, ei, A);
  reach2_kernel<<<4096,256, 0, stream>>>(A, M);
  fattn_kernel<<<1536, 256, 0, stream>>>(M, QKV, Vth, attP, Lp);
  outln_kernel<<<256,  256, 0, stream>>>(attP, Lp, Wtb + (size_t)3*256*256, bo, x, lnw, lnb, (float*)d_out);
}